// Round 1
// baseline (2679.928 us; speedup 1.0000x reference)
//
#include <hip/hip_runtime.h>
#include <math.h>

#define B_  2
#define S_  2048
#define D_  1024
#define H_  16
#define DK_ 64
#define FF_ 4096
#define NEG_ -1000000000.0f

// ---------------- LayerNorm: one block (256 thr) per row of D=1024 ----------------
__global__ void ln_kernel(const float* __restrict__ x, const float* __restrict__ g,
                          const float* __restrict__ b, float* __restrict__ out) {
    int row = blockIdx.x;
    int t = threadIdx.x;
    const float* xr = x + (size_t)row * D_;
    __shared__ float red[256];

    float s = 0.f;
    for (int i = t; i < D_; i += 256) s += xr[i];
    red[t] = s; __syncthreads();
    for (int off = 128; off > 0; off >>= 1) {
        if (t < off) red[t] += red[t + off];
        __syncthreads();
    }
    float mu = red[0] * (1.0f / D_);
    __syncthreads();

    float vs = 0.f;
    for (int i = t; i < D_; i += 256) { float d = xr[i] - mu; vs += d * d; }
    red[t] = vs; __syncthreads();
    for (int off = 128; off > 0; off >>= 1) {
        if (t < off) red[t] += red[t + off];
        __syncthreads();
    }
    float rstd = rsqrtf(red[0] * (1.0f / D_) + 1e-5f);

    float* outr = out + (size_t)row * D_;
    for (int i = t; i < D_; i += 256)
        outr[i] = (xr[i] - mu) * rstd * g[i] + b[i];
}

// ---------------- fp32 tiled GEMM: C[M,N] = A[M,K] @ W[K,N] + bias, epilogues ------
// EPI: 0 = bias only; 1 = bias + residual R; 2 = bias + exact GELU; 3 = bias + QKV scatter
// 64x64 tile, BK=16, 256 threads, 4x4 microtile per thread.
template <int EPI>
__global__ void gemm64(const float* __restrict__ A, const float* __restrict__ W,
                       const float* __restrict__ bias, const float* __restrict__ R,
                       float* __restrict__ C, int M, int N, int K) {
    __shared__ float As[16][64];
    __shared__ float Bs[16][64];
    int tid = threadIdx.x;
    int tx = tid & 15, ty = tid >> 4;
    int m0 = blockIdx.y * 64, n0 = blockIdx.x * 64;

    float acc[4][4] = {};

    for (int k0 = 0; k0 < K; k0 += 16) {
#pragma unroll
        for (int i = 0; i < 4; i++) {
            int li = tid + 256 * i;
            int am = li >> 4, ak = li & 15;
            As[ak][am] = A[(size_t)(m0 + am) * K + k0 + ak];
            int bk = li >> 6, bn = li & 63;
            Bs[bk][bn] = W[(size_t)(k0 + bk) * N + n0 + bn];
        }
        __syncthreads();
#pragma unroll
        for (int kk = 0; kk < 16; kk++) {
            float ra[4], rb[4];
#pragma unroll
            for (int a = 0; a < 4; a++) ra[a] = As[kk][ty * 4 + a];
#pragma unroll
            for (int b2 = 0; b2 < 4; b2++) rb[b2] = Bs[kk][tx * 4 + b2];
#pragma unroll
            for (int a = 0; a < 4; a++)
#pragma unroll
                for (int b2 = 0; b2 < 4; b2++) acc[a][b2] += ra[a] * rb[b2];
        }
        __syncthreads();
    }

#pragma unroll
    for (int a = 0; a < 4; a++) {
#pragma unroll
        for (int b2 = 0; b2 < 4; b2++) {
            int m = m0 + ty * 4 + a;
            int n = n0 + tx * 4 + b2;
            float v = acc[a][b2] + bias[n];
            if (EPI == 1) v += R[(size_t)m * N + n];
            if (EPI == 2) v = 0.5f * v * (1.0f + erff(v * 0.70710678118654752f));
            if (EPI == 3) {
                // m -> (b, s), n -> (h, dk); write [B,H,S,DK]
                int bb = m / S_, ss = m % S_;
                int hh = n / DK_, dk = n % DK_;
                C[((((size_t)bb * H_ + hh) * S_) + ss) * DK_ + dk] = v;
            } else {
                C[(size_t)m * N + n] = v;
            }
        }
    }
}

// ---------------- Sparse strided attention: one wave per (b,h,i) -------------------
// allowed j: j in [max(0,i-128), i]  plus  j = i - 256 - 128*e (e >= 0, j >= 0)
__global__ void attn_kernel(const float* __restrict__ q, const float* __restrict__ k,
                            const float* __restrict__ v, const int* __restrict__ mask,
                            float* __restrict__ o) {
    int i = blockIdx.x;          // query position
    int bh = blockIdx.y;         // b*H + h
    int b = bh >> 4, h = bh & 15;
    int t = threadIdx.x;         // 0..63

    const float* qr = q + ((size_t)bh * S_ + i) * DK_;
    const float* kb = k + (size_t)bh * S_ * DK_;
    const float* vb = v + (size_t)bh * S_ * DK_;

    __shared__ float qs[DK_];
    __shared__ float sc[160];
    __shared__ float red[64];

    qs[t] = qr[t];
    __syncthreads();

    int jlo = (i - 128 > 0) ? (i - 128) : 0;
    int w = i - jlo + 1;
    int nex = (i >= 256) ? (((i - 256) >> 7) + 1) : 0;
    int total = w + nex;

    for (int idx = t; idx < total; idx += 64) {
        int j = (idx < w) ? (jlo + idx) : (i - 256 - ((idx - w) << 7));
        const float* kr = kb + (size_t)j * DK_;
        float s = 0.f;
#pragma unroll
        for (int d2 = 0; d2 < DK_; d2++) s += qs[d2] * kr[d2];
        s *= 0.125f;  // 1/sqrt(DK)
        if (mask[(size_t)i * S_ + j] == 0) s = NEG_;
        sc[idx] = s;
    }
    __syncthreads();

    // max
    float mx = -INFINITY;
    for (int idx = t; idx < total; idx += 64) mx = fmaxf(mx, sc[idx]);
    red[t] = mx; __syncthreads();
    for (int off = 32; off > 0; off >>= 1) {
        if (t < off) red[t] = fmaxf(red[t], red[t + off]);
        __syncthreads();
    }
    mx = red[0]; __syncthreads();

    // exp + sum
    float sum = 0.f;
    for (int idx = t; idx < total; idx += 64) {
        float e = expf(sc[idx] - mx);
        sc[idx] = e;
        sum += e;
    }
    red[t] = sum; __syncthreads();
    for (int off = 32; off > 0; off >>= 1) {
        if (t < off) red[t] += red[t + off];
        __syncthreads();
    }
    float inv = 1.0f / red[0];
    __syncthreads();

    // o[dk=t] = sum_j p_j * v[j][t]
    float acc = 0.f;
    for (int idx = 0; idx < total; idx++) {
        int j = (idx < w) ? (jlo + idx) : (i - 256 - ((idx - w) << 7));
        acc += sc[idx] * vb[(size_t)j * DK_ + t];
    }
    // write attention output in [B,S,D] layout (concat heads)
    o[((size_t)b * S_ + i) * D_ + h * DK_ + t] = acc * inv;
}

extern "C" void kernel_launch(void* const* d_in, const int* in_sizes, int n_in,
                              void* d_out, int out_size, void* d_ws, size_t ws_size,
                              hipStream_t stream) {
    const float* x    = (const float*)d_in[0];
    const int*   mask = (const int*)  d_in[1];
    const float* Wq   = (const float*)d_in[2];
    const float* bq   = (const float*)d_in[3];
    const float* Wk   = (const float*)d_in[4];
    const float* bk   = (const float*)d_in[5];
    const float* Wv   = (const float*)d_in[6];
    const float* bv   = (const float*)d_in[7];
    const float* Wo   = (const float*)d_in[8];
    const float* bo   = (const float*)d_in[9];
    const float* W1   = (const float*)d_in[10];
    const float* bf1  = (const float*)d_in[11];
    const float* W2   = (const float*)d_in[12];
    const float* bf2  = (const float*)d_in[13];
    const float* g1   = (const float*)d_in[14];
    const float* bl1  = (const float*)d_in[15];
    const float* g2   = (const float*)d_in[16];
    const float* bl2  = (const float*)d_in[17];

    float* out = (float*)d_out;

    const size_t SZ = (size_t)B_ * S_ * D_;  // 4,194,304 floats
    float* ws  = (float*)d_ws;
    float* n1  = ws;            // [B,S,D]
    float* qb  = ws + SZ;       // [B,H,S,DK]
    float* kb  = ws + 2 * SZ;   // [B,H,S,DK]
    float* vb  = ws + 3 * SZ;   // [B,H,S,DK]
    float* ob  = n1;            // reuse: attention out [B,S,D]
    float* x1  = qb;            // reuse: post-attn residual [B,S,D]
    float* n2  = kb;            // reuse: LN2 out [B,S,D]
    float* ff1 = ws + 4 * SZ;   // [B,S,FF] 16,777,216 floats

    const int M = B_ * S_;  // 4096

    // 1. n1 = LN(x; g1, bl1)
    ln_kernel<<<M, 256, 0, stream>>>(x, g1, bl1, n1);

    // 2. q/k/v = n1 @ W{q,k,v} + b, scattered to [B,H,S,DK]
    dim3 gProj(D_ / 64, M / 64);
    gemm64<3><<<gProj, 256, 0, stream>>>(n1, Wq, bq, nullptr, qb, M, D_, D_);
    gemm64<3><<<gProj, 256, 0, stream>>>(n1, Wk, bk, nullptr, kb, M, D_, D_);
    gemm64<3><<<gProj, 256, 0, stream>>>(n1, Wv, bv, nullptr, vb, M, D_, D_);

    // 3. sparse attention -> ob [B,S,D]
    attn_kernel<<<dim3(S_, B_ * H_), 64, 0, stream>>>(qb, kb, vb, mask, ob);

    // 4. x1 = x + ob @ Wo + bo
    gemm64<1><<<gProj, 256, 0, stream>>>(ob, Wo, bo, x, x1, M, D_, D_);

    // 5. n2 = LN(x1; g2, bl2)
    ln_kernel<<<M, 256, 0, stream>>>(x1, g2, bl2, n2);

    // 6. ff1 = GELU(n2 @ W1 + bf1)   [B,S,FF]
    dim3 gFF1(FF_ / 64, M / 64);
    gemm64<2><<<gFF1, 256, 0, stream>>>(n2, W1, bf1, nullptr, ff1, M, FF_, D_);

    // 7. out = x1 + ff1 @ W2 + bf2
    gemm64<1><<<gProj, 256, 0, stream>>>(ff1, W2, bf2, x1, out, M, D_, FF_);
}

// Round 2
// 992.919 us; speedup vs baseline: 2.6990x; 2.6990x over previous
//
#include <hip/hip_runtime.h>
#include <math.h>

typedef unsigned int u32;

#define B_  2
#define S_  2048
#define D_  1024
#define H_  16
#define DK_ 64
#define FF_ 4096
#define NEG_ -1000000000.0f

typedef __attribute__((ext_vector_type(8))) short short8;
typedef __attribute__((ext_vector_type(4))) float floatx4;

__device__ inline unsigned short f2b(float f) {
    union { float f; u32 u; } v; v.f = f;
    u32 r = (v.u + 0x7fffu + ((v.u >> 16) & 1u)) >> 16;
    return (unsigned short)r;
}
__device__ inline float b2f(unsigned short b) {
    union { u32 u; float f; } v; v.u = ((u32)b) << 16;
    return v.f;
}

__device__ inline void gl_lds16(const unsigned short* g, unsigned short* l) {
    __builtin_amdgcn_global_load_lds((const __attribute__((address_space(1))) u32*)g,
                                     (__attribute__((address_space(3))) u32*)l, 16, 0, 0);
}

// ---------------- weight transpose + fp32->bf16: Wt[n][k] = bf16(W[k][n]) ----------
__global__ void tconv(const float* __restrict__ Wm, unsigned short* __restrict__ Wt,
                      int K, int N) {
    __shared__ float tile[32][33];
    int n0 = blockIdx.x * 32, k0 = blockIdx.y * 32;
    int tx = threadIdx.x & 31, ty = threadIdx.x >> 5;  // 32x8
#pragma unroll
    for (int r = 0; r < 32; r += 8)
        tile[ty + r][tx] = Wm[(size_t)(k0 + ty + r) * N + n0 + tx];
    __syncthreads();
#pragma unroll
    for (int r = 0; r < 32; r += 8)
        Wt[(size_t)(n0 + ty + r) * K + k0 + tx] = f2b(tile[tx][ty + r]);
}

// ---------------- LayerNorm -> bf16 out ----------------
__global__ void ln_bf16(const float* __restrict__ x, const float* __restrict__ g,
                        const float* __restrict__ b, unsigned short* __restrict__ out) {
    int row = blockIdx.x;
    int t = threadIdx.x;
    const float* xr = x + (size_t)row * D_;
    __shared__ float red[256];

    float s = 0.f;
    for (int i = t; i < D_; i += 256) s += xr[i];
    red[t] = s; __syncthreads();
    for (int off = 128; off > 0; off >>= 1) {
        if (t < off) red[t] += red[t + off];
        __syncthreads();
    }
    float mu = red[0] * (1.0f / D_);
    __syncthreads();

    float vs = 0.f;
    for (int i = t; i < D_; i += 256) { float d = xr[i] - mu; vs += d * d; }
    red[t] = vs; __syncthreads();
    for (int off = 128; off > 0; off >>= 1) {
        if (t < off) red[t] += red[t + off];
        __syncthreads();
    }
    float rstd = rsqrtf(red[0] * (1.0f / D_) + 1e-5f);

    unsigned short* outr = out + (size_t)row * D_;
    for (int i = t; i < D_; i += 256)
        outr[i] = f2b((xr[i] - mu) * rstd * g[i] + b[i]);
}

// ---------------- bf16 MFMA GEMM: C = A[M,K] @ Bt[N,K]^T + bias -------------------
// EPI 0: fp32 QKV scatter to [B,H,S,DK]; EPI 1: fp32 + residual R; EPI 2: bf16 GELU
template <int EPI>
__global__ __launch_bounds__(256)
void gemm_bt(const unsigned short* __restrict__ A, const unsigned short* __restrict__ Bt,
             const float* __restrict__ bias, const float* __restrict__ R,
             void* __restrict__ Cv, int M, int N, int K) {
    __shared__ unsigned short As[128 * 32];
    __shared__ unsigned short Bs[128 * 32];
    int tid = threadIdx.x;
    int lane = tid & 63, w = tid >> 6;
    int wm = w >> 1, wn = w & 1;
    int m0 = blockIdx.y * 128, n0 = blockIdx.x * 128;

    floatx4 acc[4][4];
#pragma unroll
    for (int a = 0; a < 4; a++)
#pragma unroll
        for (int b2 = 0; b2 < 4; b2++) acc[a][b2] = (floatx4){0.f, 0.f, 0.f, 0.f};

    int arow = lane >> 2, acol = (lane & 3) * 8;
    const unsigned short* Ag0 = A + (size_t)(m0 + w * 16 + arow) * K + acol;
    const unsigned short* Bg0 = Bt + (size_t)(n0 + w * 16 + arow) * K + acol;
    unsigned short* Al = As + (w * 16) * 32;  // wave-uniform LDS base
    unsigned short* Bl = Bs + (w * 16) * 32;

    for (int k0 = 0; k0 < K; k0 += 32) {
        __syncthreads();
        gl_lds16(Ag0 + k0, Al);
        gl_lds16(Ag0 + k0 + (size_t)64 * K, Al + 64 * 32);
        gl_lds16(Bg0 + k0, Bl);
        gl_lds16(Bg0 + k0 + (size_t)64 * K, Bl + 64 * 32);
        __syncthreads();
        short8 fa[4], fb[4];
#pragma unroll
        for (int a = 0; a < 4; a++)
            fa[a] = *(const short8*)&As[(wm * 64 + a * 16 + (lane & 15)) * 32 + (lane >> 4) * 8];
#pragma unroll
        for (int b2 = 0; b2 < 4; b2++)
            fb[b2] = *(const short8*)&Bs[(wn * 64 + b2 * 16 + (lane & 15)) * 32 + (lane >> 4) * 8];
#pragma unroll
        for (int a = 0; a < 4; a++)
#pragma unroll
            for (int b2 = 0; b2 < 4; b2++)
                acc[a][b2] = __builtin_amdgcn_mfma_f32_16x16x32_bf16(fa[a], fb[b2], acc[a][b2], 0, 0, 0);
    }

    int mb = m0 + wm * 64, nb = n0 + wn * 64;
#pragma unroll
    for (int a = 0; a < 4; a++) {
#pragma unroll
        for (int b2 = 0; b2 < 4; b2++) {
            int mrow = mb + a * 16 + (lane >> 4) * 4;
            int ncol = nb + b2 * 16 + (lane & 15);
            float bv = bias[ncol];
#pragma unroll
            for (int r = 0; r < 4; r++) {
                int m = mrow + r;
                float vvv = acc[a][b2][r] + bv;
                if (EPI == 0) {
                    int bb = m >> 11, ss = m & 2047, hh = ncol >> 6, dk = ncol & 63;
                    ((float*)Cv)[((((size_t)bb * H_ + hh) * S_) + ss) * DK_ + dk] = vvv;
                } else if (EPI == 1) {
                    ((float*)Cv)[(size_t)m * N + ncol] = vvv + R[(size_t)m * N + ncol];
                } else {
                    ((unsigned short*)Cv)[(size_t)m * N + ncol] =
                        f2b(0.5f * vvv * (1.f + erff(vvv * 0.70710678118654752f)));
                }
            }
        }
    }
}

// ---------------- tiled sparse attention: block = (b,h, 64 queries) ---------------
__global__ __launch_bounds__(256)
void attn2(const float* __restrict__ q, const float* __restrict__ k,
           const float* __restrict__ v, const int* __restrict__ mask,
           unsigned short* __restrict__ ob) {
    __shared__ unsigned short Kw[192 * 66];
    __shared__ unsigned short Vw[192 * 66];
    __shared__ unsigned short qs[64 * 64];
    __shared__ float sc[4][160];

    int i0 = blockIdx.x * 64;
    int bh = blockIdx.y;
    int b = bh >> 4, h = bh & 15;
    int t = threadIdx.x, lane = t & 63, w = t >> 6;

    const float* qb = q + (size_t)bh * S_ * DK_;
    const float* kb = k + (size_t)bh * S_ * DK_;
    const float* vb = v + (size_t)bh * S_ * DK_;

    int wlo = (i0 - 128 > 0) ? (i0 - 128) : 0;
    int wn = i0 + 64 - wlo;  // <= 192 window rows

    for (int e = t; e < wn * DK_; e += 256) {
        int r = e >> 6, d = e & 63;
        Kw[r * 66 + d] = f2b(kb[(size_t)(wlo + r) * DK_ + d]);
        Vw[r * 66 + d] = f2b(vb[(size_t)(wlo + r) * DK_ + d]);
    }
    for (int e = t; e < 64 * 64; e += 256)
        qs[e] = f2b(qb[(size_t)(i0 + (e >> 6)) * DK_ + (e & 63)]);
    __syncthreads();

    for (int qq = 0; qq < 16; qq++) {
        int i = i0 + w * 16 + qq;
        int qloc = (w * 16 + qq) * 64;
        int jlo = (i - 128 > 0) ? (i - 128) : 0;
        int wcnt = i - jlo + 1;
        int nex = (i >= 256) ? (((i - 256) >> 7) + 1) : 0;
        int total = wcnt + nex;

        float mx = -1e30f;
        for (int idx = lane; idx < total; idx += 64) {
            int j = (idx < wcnt) ? (jlo + idx) : (i - 256 - ((idx - wcnt) << 7));
            float s = 0.f;
            if (idx < wcnt) {
                const unsigned short* kr = &Kw[(j - wlo) * 66];
#pragma unroll
                for (int d = 0; d < DK_; d++) s += b2f(qs[qloc + d]) * b2f(kr[d]);
            } else {
                const float4* kr4 = (const float4*)(kb + (size_t)j * DK_);
#pragma unroll
                for (int d4 = 0; d4 < 16; d4++) {
                    float4 kk = kr4[d4];
                    s += b2f(qs[qloc + d4 * 4 + 0]) * kk.x + b2f(qs[qloc + d4 * 4 + 1]) * kk.y
                       + b2f(qs[qloc + d4 * 4 + 2]) * kk.z + b2f(qs[qloc + d4 * 4 + 3]) * kk.w;
                }
            }
            s *= 0.125f;
            if (mask[(size_t)i * S_ + j] == 0) s = NEG_;
            sc[w][idx] = s;
            mx = fmaxf(mx, s);
        }
        for (int m2 = 32; m2; m2 >>= 1) mx = fmaxf(mx, __shfl_xor(mx, m2, 64));

        asm volatile("s_waitcnt lgkmcnt(0)" ::: "memory");
        __builtin_amdgcn_wave_barrier();

        float sum = 0.f;
        for (int idx = lane; idx < total; idx += 64) {
            float e = __expf(sc[w][idx] - mx);
            sc[w][idx] = e;
            sum += e;
        }
        for (int m2 = 32; m2; m2 >>= 1) sum += __shfl_xor(sum, m2, 64);
        float inv = 1.f / sum;

        asm volatile("s_waitcnt lgkmcnt(0)" ::: "memory");
        __builtin_amdgcn_wave_barrier();

        float acc = 0.f;
        for (int idx = 0; idx < total; idx++) {
            int j = (idx < wcnt) ? (jlo + idx) : (i - 256 - ((idx - wcnt) << 7));
            float p = sc[w][idx];
            float vv = (j >= wlo) ? b2f(Vw[(j - wlo) * 66 + lane]) : vb[(size_t)j * DK_ + lane];
            acc += p * vv;
        }
        ob[((size_t)b * S_ + i) * D_ + h * DK_ + lane] = f2b(acc * inv);
    }
}

extern "C" void kernel_launch(void* const* d_in, const int* in_sizes, int n_in,
                              void* d_out, int out_size, void* d_ws, size_t ws_size,
                              hipStream_t stream) {
    const float* x    = (const float*)d_in[0];
    const int*   mask = (const int*)  d_in[1];
    const float* Wq   = (const float*)d_in[2];
    const float* bq   = (const float*)d_in[3];
    const float* Wk   = (const float*)d_in[4];
    const float* bk   = (const float*)d_in[5];
    const float* Wv   = (const float*)d_in[6];
    const float* bv   = (const float*)d_in[7];
    const float* Wo   = (const float*)d_in[8];
    const float* bo   = (const float*)d_in[9];
    const float* W1   = (const float*)d_in[10];
    const float* bf1  = (const float*)d_in[11];
    const float* W2   = (const float*)d_in[12];
    const float* bf2  = (const float*)d_in[13];
    const float* g1   = (const float*)d_in[14];
    const float* bl1  = (const float*)d_in[15];
    const float* g2   = (const float*)d_in[16];
    const float* bl2  = (const float*)d_in[17];

    char* wsb = (char*)d_ws;
    const size_t MB = 1024 * 1024;
    unsigned short* WtQ  = (unsigned short*)(wsb + 0);
    unsigned short* WtK  = (unsigned short*)(wsb + 2 * MB);
    unsigned short* WtV  = (unsigned short*)(wsb + 4 * MB);
    unsigned short* WtO  = (unsigned short*)(wsb + 6 * MB);
    unsigned short* Wt1  = (unsigned short*)(wsb + 8 * MB);
    unsigned short* Wt2  = (unsigned short*)(wsb + 16 * MB);
    unsigned short* n1b  = (unsigned short*)(wsb + 24 * MB);
    float*          qf   = (float*)(wsb + 32 * MB);
    float*          kf   = (float*)(wsb + 48 * MB);
    float*          vf   = (float*)(wsb + 64 * MB);
    unsigned short* obb  = (unsigned short*)(wsb + 80 * MB);
    float*          x1   = (float*)(wsb + 88 * MB);
    unsigned short* n2b  = (unsigned short*)(wsb + 104 * MB);
    unsigned short* ff1b = (unsigned short*)(wsb + 24 * MB);  // reuse (n1b/qf dead by then)

    const int M = B_ * S_;  // 4096

    // 0. weight transpose + convert
    tconv<<<dim3(32, 32),  256, 0, stream>>>(Wq, WtQ, 1024, 1024);
    tconv<<<dim3(32, 32),  256, 0, stream>>>(Wk, WtK, 1024, 1024);
    tconv<<<dim3(32, 32),  256, 0, stream>>>(Wv, WtV, 1024, 1024);
    tconv<<<dim3(32, 32),  256, 0, stream>>>(Wo, WtO, 1024, 1024);
    tconv<<<dim3(128, 32), 256, 0, stream>>>(W1, Wt1, 1024, 4096);
    tconv<<<dim3(32, 128), 256, 0, stream>>>(W2, Wt2, 4096, 1024);

    // 1. LN1 -> bf16
    ln_bf16<<<M, 256, 0, stream>>>(x, g1, bl1, n1b);

    // 2. QKV projections (scatter fp32 [B,H,S,DK])
    gemm_bt<0><<<dim3(8, 32), 256, 0, stream>>>(n1b, WtQ, bq, nullptr, qf, M, D_, D_);
    gemm_bt<0><<<dim3(8, 32), 256, 0, stream>>>(n1b, WtK, bk, nullptr, kf, M, D_, D_);
    gemm_bt<0><<<dim3(8, 32), 256, 0, stream>>>(n1b, WtV, bv, nullptr, vf, M, D_, D_);

    // 3. sparse attention -> bf16 [B,S,D]
    attn2<<<dim3(32, 32), 256, 0, stream>>>(qf, kf, vf, mask, obb);

    // 4. x1 = x + ob @ Wo + bo (fp32)
    gemm_bt<1><<<dim3(8, 32), 256, 0, stream>>>(obb, WtO, bo, x, x1, M, D_, D_);

    // 5. LN2 -> bf16
    ln_bf16<<<M, 256, 0, stream>>>(x1, g2, bl2, n2b);

    // 6. ff1 = GELU(n2 @ W1 + bf1) -> bf16
    gemm_bt<2><<<dim3(32, 32), 256, 0, stream>>>(n2b, Wt1, bf1, nullptr, ff1b, M, FF_, D_);

    // 7. out = x1 + ff1 @ W2 + bf2 (fp32)
    gemm_bt<1><<<dim3(8, 32), 256, 0, stream>>>(ff1b, Wt2, bf2, x1, (float*)d_out, M, D_, FF_);
}

// Round 3
// 476.065 us; speedup vs baseline: 5.6293x; 2.0857x over previous
//
#include <hip/hip_runtime.h>
#include <math.h>

typedef unsigned int u32;
typedef unsigned short u16;

#define B_  2
#define S_  2048
#define D_  1024
#define H_  16
#define DK_ 64
#define FF_ 4096
#define NEG_ -1000000000.0f

typedef __attribute__((ext_vector_type(8))) short short8;
typedef __attribute__((ext_vector_type(4))) float floatx4;

__device__ inline u16 f2b(float f) {
    union { float f; u32 u; } v; v.f = f;
    u32 r = (v.u + 0x7fffu + ((v.u >> 16) & 1u)) >> 16;
    return (u16)r;
}
__device__ inline float b2f(u16 b) {
    union { u32 u; float f; } v; v.u = ((u32)b) << 16;
    return v.f;
}

__device__ inline void gl_lds16(const u16* g, u16* l) {
    __builtin_amdgcn_global_load_lds((const __attribute__((address_space(1))) u32*)g,
                                     (__attribute__((address_space(3))) u32*)l, 16, 0, 0);
}

// ---------------- weight transpose + fp32->bf16: Wt[n][k] = bf16(W[k][n]) ----------
__global__ void tconv(const float* __restrict__ Wm, u16* __restrict__ Wt, int K, int N) {
    __shared__ float tile[32][33];
    int n0 = blockIdx.x * 32, k0 = blockIdx.y * 32;
    int tx = threadIdx.x & 31, ty = threadIdx.x >> 5;  // 32x8
#pragma unroll
    for (int r = 0; r < 32; r += 8)
        tile[ty + r][tx] = Wm[(size_t)(k0 + ty + r) * N + n0 + tx];
    __syncthreads();
#pragma unroll
    for (int r = 0; r < 32; r += 8)
        Wt[(size_t)(n0 + ty + r) * K + k0 + tx] = f2b(tile[tx][ty + r]);
}

__global__ void catbias(const float* __restrict__ bq, const float* __restrict__ bk,
                        const float* __restrict__ bv, float* __restrict__ out) {
    int i = blockIdx.x * 256 + threadIdx.x;
    float v = (i < 1024) ? bq[i] : (i < 2048) ? bk[i - 1024] : bv[i - 2048];
    out[i] = v;
}

// ---------------- LayerNorm -> bf16 out ----------------
__global__ void ln_bf16(const float* __restrict__ x, const float* __restrict__ g,
                        const float* __restrict__ b, u16* __restrict__ out) {
    int row = blockIdx.x;
    int t = threadIdx.x;
    const float* xr = x + (size_t)row * D_;
    __shared__ float red[256];

    float s = 0.f;
    for (int i = t; i < D_; i += 256) s += xr[i];
    red[t] = s; __syncthreads();
    for (int off = 128; off > 0; off >>= 1) {
        if (t < off) red[t] += red[t + off];
        __syncthreads();
    }
    float mu = red[0] * (1.0f / D_);
    __syncthreads();

    float vs = 0.f;
    for (int i = t; i < D_; i += 256) { float d = xr[i] - mu; vs += d * d; }
    red[t] = vs; __syncthreads();
    for (int off = 128; off > 0; off >>= 1) {
        if (t < off) red[t] += red[t + off];
        __syncthreads();
    }
    float rstd = rsqrtf(red[0] * (1.0f / D_) + 1e-5f);

    u16* outr = out + (size_t)row * D_;
    for (int i = t; i < D_; i += 256)
        outr[i] = f2b((xr[i] - mu) * rstd * g[i] + b[i]);
}

// ---------------- bf16 MFMA GEMM: C = A[M,K] @ Bt[N,K]^T + bias -------------------
// EPI 0: bf16 fused-QKV scatter to 3x [B,H,S,DK]; EPI 1: fp32 + residual; EPI 2: bf16 GELU
template <int EPI>
__global__ __launch_bounds__(256)
void gemm_bt(const u16* __restrict__ A, const u16* __restrict__ Bt,
             const float* __restrict__ bias, const float* __restrict__ R,
             void* __restrict__ Cv, int M, int N, int K) {
    __shared__ u16 As[128 * 32];
    __shared__ u16 Bs[128 * 32];
    int tid = threadIdx.x;
    int lane = tid & 63, w = tid >> 6;
    int wm = w >> 1, wn = w & 1;
    int m0 = blockIdx.y * 128, n0 = blockIdx.x * 128;

    floatx4 acc[4][4];
#pragma unroll
    for (int a = 0; a < 4; a++)
#pragma unroll
        for (int b2 = 0; b2 < 4; b2++) acc[a][b2] = (floatx4){0.f, 0.f, 0.f, 0.f};

    int arow = lane >> 2, acol = (lane & 3) * 8;
    const u16* Ag0 = A + (size_t)(m0 + w * 16 + arow) * K + acol;
    const u16* Bg0 = Bt + (size_t)(n0 + w * 16 + arow) * K + acol;
    u16* Al = As + (w * 16) * 32;
    u16* Bl = Bs + (w * 16) * 32;

    for (int k0 = 0; k0 < K; k0 += 32) {
        __syncthreads();
        gl_lds16(Ag0 + k0, Al);
        gl_lds16(Ag0 + k0 + (size_t)64 * K, Al + 64 * 32);
        gl_lds16(Bg0 + k0, Bl);
        gl_lds16(Bg0 + k0 + (size_t)64 * K, Bl + 64 * 32);
        __syncthreads();
        short8 fa[4], fb[4];
#pragma unroll
        for (int a = 0; a < 4; a++)
            fa[a] = *(const short8*)&As[(wm * 64 + a * 16 + (lane & 15)) * 32 + (lane >> 4) * 8];
#pragma unroll
        for (int b2 = 0; b2 < 4; b2++)
            fb[b2] = *(const short8*)&Bs[(wn * 64 + b2 * 16 + (lane & 15)) * 32 + (lane >> 4) * 8];
#pragma unroll
        for (int a = 0; a < 4; a++)
#pragma unroll
            for (int b2 = 0; b2 < 4; b2++)
                acc[a][b2] = __builtin_amdgcn_mfma_f32_16x16x32_bf16(fa[a], fb[b2], acc[a][b2], 0, 0, 0);
    }

    int mb = m0 + wm * 64, nb = n0 + wn * 64;
#pragma unroll
    for (int a = 0; a < 4; a++) {
#pragma unroll
        for (int b2 = 0; b2 < 4; b2++) {
            int mrow = mb + a * 16 + (lane >> 4) * 4;
            int ncol = nb + b2 * 16 + (lane & 15);
            float bv = bias[ncol];
#pragma unroll
            for (int r = 0; r < 4; r++) {
                int m = mrow + r;
                float vvv = acc[a][b2][r] + bv;
                if (EPI == 0) {
                    int which = ncol >> 10, col = ncol & 1023;
                    int bb = m >> 11, ss = m & 2047, hh = col >> 6, dk = col & 63;
                    ((u16*)Cv)[(size_t)which * ((size_t)B_ * S_ * D_) +
                               ((((size_t)bb * H_ + hh) * S_) + ss) * DK_ + dk] = f2b(vvv);
                } else if (EPI == 1) {
                    ((float*)Cv)[(size_t)m * N + ncol] = vvv + R[(size_t)m * N + ncol];
                } else {
                    ((u16*)Cv)[(size_t)m * N + ncol] =
                        f2b(0.5f * vvv * (1.f + erff(vvv * 0.70710678118654752f)));
                }
            }
        }
    }
}

// ---------------- MFMA sparse strided attention: block = (b,h, 64 queries) --------
// window: dense 64 x wn scores via MFMA; strided bands: uniform diagonals via VALU.
__global__ __launch_bounds__(256)
void attn3(const u16* __restrict__ q, const u16* __restrict__ k,
           const u16* __restrict__ v, const int* __restrict__ mask,
           u16* __restrict__ ob) {
    __shared__ u16 Qs[64 * 72];       // Q rows, stride 72 (pad kills bank hotspots)
    __shared__ u16 Kw[192 * 72];      // K window rows; overlaid by P[64 x 200] after scores
    __shared__ u16 Vt[64 * 200];      // V window transposed [dim][j], stride 200
    __shared__ u16 Vband[4][16 * 64]; // per-wave strided-band V rows
    __shared__ float sb[64][17];      // band scores per query

    const int i0 = blockIdx.x * 64;
    const int bh = blockIdx.y;
    const int b  = bh >> 4, h = bh & 15;
    const int t  = threadIdx.x;
    const int lane = t & 63, w = t >> 6;
    const int c = lane & 15, g = lane >> 4;
    const int qloc16 = w * 16;

    const u16* qg = q + ((size_t)bh * S_ + i0) * DK_;
    const u16* kg = k + (size_t)bh * S_ * DK_;
    const u16* vg = v + (size_t)bh * S_ * DK_;

    const int wlo = (i0 >= 128) ? i0 - 128 : 0;
    const int wn  = i0 + 64 - wlo;             // 64 / 128 / 192
    const int nb  = (i0 >= 256) ? (i0 >> 7) - 1 : 0;
    const int jb0 = i0 & 127;
    const int dd0 = i0 - wlo;

    // ---- P0: stage Qs, Kw (row-major), Vt (transposed, zero-padded cols >= wn)
    for (int e = t; e < 64 * 8; e += 256) {
        int row = e >> 3, dc = e & 7;
        *(short8*)&Qs[row * 72 + dc * 8] = *(const short8*)(qg + row * 64 + dc * 8);
    }
    for (int e = t; e < wn * 8; e += 256) {
        int row = e >> 3, dc = e & 7;
        *(short8*)&Kw[row * 72 + dc * 8] = *(const short8*)(kg + (size_t)(wlo + row) * 64 + dc * 8);
    }
#pragma unroll
    for (int dc = 0; dc < 8; dc++) {
        for (int jl = t; jl < 192; jl += 256) {
            short8 val = {0, 0, 0, 0, 0, 0, 0, 0};
            if (jl < wn) val = *(const short8*)(vg + (size_t)(wlo + jl) * 64 + dc * 8);
#pragma unroll
            for (int i = 0; i < 8; i++) Vt[(dc * 8 + i) * 200 + jl] = (u16)val[i];
        }
    }
    __syncthreads();

    // ---- P1: strided band scores (uniform diagonals) -> sb[qloc][m]
    for (int m = 0; m < nb; m++) {
        int jb = jb0 + (m << 7);
        int jrow = jb + qloc16 + c;  // K row for query (i0 + qloc16 + c)
        float p = 0.f;
#pragma unroll
        for (int kc = 0; kc < 2; kc++) {
            short8 kv = *(const short8*)(kg + (size_t)jrow * 64 + kc * 32 + g * 8);
            short8 qv = *(const short8*)&Qs[(qloc16 + c) * 72 + kc * 32 + g * 8];
#pragma unroll
            for (int i = 0; i < 8; i++) p += b2f((u16)qv[i]) * b2f((u16)kv[i]);
        }
        p += __shfl_xor(p, 16);
        p += __shfl_xor(p, 32);
        if (g == 0) {
            int qi = i0 + qloc16 + c;
            float s = p * 0.125f;
            if (mask[(size_t)qi * S_ + jrow] == 0) s = NEG_;
            sb[qloc16 + c][m] = s;
        }
    }

    // ---- P2: window scores via MFMA (always 12 col-tiles; invalid cols masked)
    floatx4 sc[12];
#pragma unroll
    for (int ct = 0; ct < 12; ct++) sc[ct] = (floatx4){0.f, 0.f, 0.f, 0.f};
    short8 fa0 = *(const short8*)&Qs[(qloc16 + c) * 72 + g * 8];
    short8 fa1 = *(const short8*)&Qs[(qloc16 + c) * 72 + 32 + g * 8];
#pragma unroll
    for (int ct = 0; ct < 12; ct++) {
        short8 fb0 = *(const short8*)&Kw[(ct * 16 + c) * 72 + g * 8];
        short8 fb1 = *(const short8*)&Kw[(ct * 16 + c) * 72 + 32 + g * 8];
        sc[ct] = __builtin_amdgcn_mfma_f32_16x16x32_bf16(fa0, fb0, sc[ct], 0, 0, 0);
        sc[ct] = __builtin_amdgcn_mfma_f32_16x16x32_bf16(fa1, fb1, sc[ct], 0, 0, 0);
    }

    // ---- P3: mask + softmax (window frags + band scores)
#pragma unroll
    for (int ct = 0; ct < 12; ct++) {
        int cidx = ct * 16 + c;
        int j = wlo + cidx;
#pragma unroll
        for (int r = 0; r < 4; r++) {
            int qloc = qloc16 + g * 4 + r;
            int d = dd0 + qloc - cidx;
            float s = sc[ct][r] * 0.125f;
            bool ok = false;
            if (d >= 0 && d <= 128) ok = (mask[(size_t)(i0 + qloc) * S_ + j] != 0);
            sc[ct][r] = ok ? s : NEG_;
        }
    }

    float mv[4], inv[4];
#pragma unroll
    for (int r = 0; r < 4; r++) {
        float mm = -1e30f;
#pragma unroll
        for (int ct = 0; ct < 12; ct++) mm = fmaxf(mm, sc[ct][r]);
        mm = fmaxf(mm, __shfl_xor(mm, 1));
        mm = fmaxf(mm, __shfl_xor(mm, 2));
        mm = fmaxf(mm, __shfl_xor(mm, 4));
        mm = fmaxf(mm, __shfl_xor(mm, 8));
        int qloc = qloc16 + g * 4 + r;
        for (int m = 0; m < nb; m++) mm = fmaxf(mm, sb[qloc][m]);
        float sum = 0.f;
#pragma unroll
        for (int ct = 0; ct < 12; ct++) {
            float e = __expf(sc[ct][r] - mm);
            sc[ct][r] = e;
            sum += e;
        }
        sum += __shfl_xor(sum, 1);
        sum += __shfl_xor(sum, 2);
        sum += __shfl_xor(sum, 4);
        sum += __shfl_xor(sum, 8);
        for (int m = 0; m < nb; m++) sum += __expf(sb[qloc][m] - mm);
        mv[r] = mm;
        inv[r] = 1.f / sum;
    }

    // ---- P4: write P (unnormalized probs, bf16) over Kw; stride 200
    __syncthreads();  // all waves done reading Kw
    u16* P = Kw;
#pragma unroll
    for (int ct = 0; ct < 12; ct++) {
#pragma unroll
        for (int r = 0; r < 4; r++) {
            int qloc = qloc16 + g * 4 + r;
            P[qloc * 200 + ct * 16 + c] = f2b(sc[ct][r]);
        }
    }

    // ---- P5: window PV via MFMA (own rows only; same-wave LDS dependency)
    floatx4 o[4];
#pragma unroll
    for (int nt = 0; nt < 4; nt++) o[nt] = (floatx4){0.f, 0.f, 0.f, 0.f};
#pragma unroll
    for (int ks = 0; ks < 6; ks++) {
        short8 pa = *(const short8*)&P[(qloc16 + c) * 200 + ks * 32 + g * 8];
#pragma unroll
        for (int nt = 0; nt < 4; nt++) {
            short8 vb = *(const short8*)&Vt[(nt * 16 + c) * 200 + ks * 32 + g * 8];
            o[nt] = __builtin_amdgcn_mfma_f32_16x16x32_bf16(pa, vb, o[nt], 0, 0, 0);
        }
    }

    // ---- P6: band PV (per-wave V rows staged via global_load_lds)
    for (int m = 0; m < nb; m++) {
        int jb = jb0 + (m << 7);
        asm volatile("s_waitcnt lgkmcnt(0)" ::: "memory");
        __builtin_amdgcn_wave_barrier();
        gl_lds16(vg + (size_t)(jb + qloc16 + (lane >> 3)) * 64 + (lane & 7) * 8, &Vband[w][0]);
        gl_lds16(vg + (size_t)(jb + qloc16 + 8 + (lane >> 3)) * 64 + (lane & 7) * 8, &Vband[w][512]);
        asm volatile("s_waitcnt vmcnt(0)" ::: "memory");
        __builtin_amdgcn_wave_barrier();
#pragma unroll
        for (int r = 0; r < 4; r++) {
            int qloc = qloc16 + g * 4 + r;
            float pb = __expf(sb[qloc][m] - mv[r]);
#pragma unroll
            for (int nt = 0; nt < 4; nt++)
                o[nt][r] += pb * b2f(Vband[w][(g * 4 + r) * 64 + nt * 16 + c]);
        }
    }

    // ---- P7: normalize + write [B,S,D] bf16
#pragma unroll
    for (int nt = 0; nt < 4; nt++) {
#pragma unroll
        for (int r = 0; r < 4; r++) {
            int qi = i0 + qloc16 + g * 4 + r;
            ob[((size_t)b * S_ + qi) * D_ + h * 64 + nt * 16 + c] = f2b(o[nt][r] * inv[r]);
        }
    }
}

extern "C" void kernel_launch(void* const* d_in, const int* in_sizes, int n_in,
                              void* d_out, int out_size, void* d_ws, size_t ws_size,
                              hipStream_t stream) {
    const float* x    = (const float*)d_in[0];
    const int*   mask = (const int*)  d_in[1];
    const float* Wq   = (const float*)d_in[2];
    const float* bq   = (const float*)d_in[3];
    const float* Wk   = (const float*)d_in[4];
    const float* bk   = (const float*)d_in[5];
    const float* Wv   = (const float*)d_in[6];
    const float* bv   = (const float*)d_in[7];
    const float* Wo   = (const float*)d_in[8];
    const float* bo   = (const float*)d_in[9];
    const float* W1   = (const float*)d_in[10];
    const float* bf1  = (const float*)d_in[11];
    const float* W2   = (const float*)d_in[12];
    const float* bf2  = (const float*)d_in[13];
    const float* g1   = (const float*)d_in[14];
    const float* bl1  = (const float*)d_in[15];
    const float* g2   = (const float*)d_in[16];
    const float* bl2  = (const float*)d_in[17];

    char* wsb = (char*)d_ws;
    const size_t MB = 1024 * 1024;
    u16*   WtQKV = (u16*)(wsb + 0);          // 6 MB (Wq|Wk|Wv transposed, contiguous)
    u16*   WtO   = (u16*)(wsb + 6 * MB);     // 2 MB
    u16*   Wt1   = (u16*)(wsb + 8 * MB);     // 8 MB
    u16*   Wt2   = (u16*)(wsb + 16 * MB);    // 8 MB
    u16*   n1b   = (u16*)(wsb + 24 * MB);    // 8 MB (reused for n2b later)
    u16*   qkv   = (u16*)(wsb + 32 * MB);    // 24 MB: qb|kb|vb  (dead after attn)
    u16*   obb   = (u16*)(wsb + 56 * MB);    // 8 MB (dead after Wo gemm)
    float* x1    = (float*)(wsb + 32 * MB);  // 16 MB, overlays dead qb|kb
    u16*   ff1b  = (u16*)(wsb + 48 * MB);    // 33.5 MB, overlays dead vb|obb
    u16*   n2b   = n1b;
    float* bcat  = (float*)(wsb + 82 * MB);  // 12 KB

    const int M = B_ * S_;  // 4096
    const size_t SZ = (size_t)B_ * S_ * D_;

    // 0. weight transpose + convert, bias concat
    tconv<<<dim3(32, 32),  256, 0, stream>>>(Wq, WtQKV,            1024, 1024);
    tconv<<<dim3(32, 32),  256, 0, stream>>>(Wk, WtQKV + 1024*1024, 1024, 1024);
    tconv<<<dim3(32, 32),  256, 0, stream>>>(Wv, WtQKV + 2*1024*1024, 1024, 1024);
    tconv<<<dim3(32, 32),  256, 0, stream>>>(Wo, WtO, 1024, 1024);
    tconv<<<dim3(128, 32), 256, 0, stream>>>(W1, Wt1, 1024, 4096);
    tconv<<<dim3(32, 128), 256, 0, stream>>>(W2, Wt2, 4096, 1024);
    catbias<<<12, 256, 0, stream>>>(bq, bk, bv, bcat);

    // 1. LN1 -> bf16
    ln_bf16<<<M, 256, 0, stream>>>(x, g1, bl1, n1b);

    // 2. fused QKV projection (N=3072) -> bf16 [B,H,S,DK] x3
    gemm_bt<0><<<dim3(24, 32), 256, 0, stream>>>(n1b, WtQKV, bcat, nullptr, qkv, M, 3072, D_);

    // 3. sparse strided attention (MFMA) -> bf16 [B,S,D]
    attn3<<<dim3(32, 32), 256, 0, stream>>>(qkv, qkv + SZ, qkv + 2 * SZ, mask, obb);

    // 4. x1 = x + ob @ Wo + bo (fp32)
    gemm_bt<1><<<dim3(8, 32), 256, 0, stream>>>(obb, WtO, bo, x, x1, M, D_, D_);

    // 5. LN2 -> bf16
    ln_bf16<<<M, 256, 0, stream>>>(x1, g2, bl2, n2b);

    // 6. ff1 = GELU(n2 @ W1 + bf1) -> bf16
    gemm_bt<2><<<dim3(32, 32), 256, 0, stream>>>(n2b, Wt1, bf1, nullptr, ff1b, M, FF_, D_);

    // 7. out = x1 + ff1 @ W2 + bf2 (fp32)
    gemm_bt<1><<<dim3(8, 32), 256, 0, stream>>>(ff1b, Wt2, bf2, x1, (float*)d_out, M, D_, FF_);
}

// Round 4
// 447.278 us; speedup vs baseline: 5.9916x; 1.0644x over previous
//
#include <hip/hip_runtime.h>
#include <math.h>

typedef unsigned int u32;
typedef unsigned short u16;

#define B_  2
#define S_  2048
#define D_  1024
#define H_  16
#define DK_ 64
#define FF_ 4096
#define NEG_ -1000000000.0f

typedef __attribute__((ext_vector_type(8))) short short8;
typedef __attribute__((ext_vector_type(4))) float floatx4;
typedef __attribute__((ext_vector_type(4))) unsigned short ushort4_t;

__device__ inline u16 f2b(float f) {
    union { float f; u32 u; } v; v.f = f;
    u32 r = (v.u + 0x7fffu + ((v.u >> 16) & 1u)) >> 16;
    return (u16)r;
}
__device__ inline float b2f(u16 b) {
    union { u32 u; float f; } v; v.u = ((u32)b) << 16;
    return v.f;
}

__device__ inline void gl_lds16(const u16* g, u16* l) {
    __builtin_amdgcn_global_load_lds((const __attribute__((address_space(1))) u32*)g,
                                     (__attribute__((address_space(3))) u32*)l, 16, 0, 0);
}

// ------- 4x square (1024x1024) weight transpose+convert in one launch -------
__global__ void tconv4(const float* __restrict__ W0, const float* __restrict__ W1_,
                       const float* __restrict__ W2_, const float* __restrict__ W3,
                       u16* __restrict__ dstBase) {
    __shared__ float tile[32][33];
    int z = blockIdx.z;
    const float* Wm = (z == 0) ? W0 : (z == 1) ? W1_ : (z == 2) ? W2_ : W3;
    u16* Wt = dstBase + (size_t)z * 1024 * 1024;
    const int K = 1024, N = 1024;
    int n0 = blockIdx.x * 32, k0 = blockIdx.y * 32;
    int tx = threadIdx.x & 31, ty = threadIdx.x >> 5;
#pragma unroll
    for (int r = 0; r < 32; r += 8)
        tile[ty + r][tx] = Wm[(size_t)(k0 + ty + r) * N + n0 + tx];
    __syncthreads();
#pragma unroll
    for (int r = 0; r < 32; r += 8)
        Wt[(size_t)(n0 + ty + r) * K + k0 + tx] = f2b(tile[tx][ty + r]);
}

__global__ void tconv(const float* __restrict__ Wm, u16* __restrict__ Wt, int K, int N) {
    __shared__ float tile[32][33];
    int n0 = blockIdx.x * 32, k0 = blockIdx.y * 32;
    int tx = threadIdx.x & 31, ty = threadIdx.x >> 5;
#pragma unroll
    for (int r = 0; r < 32; r += 8)
        tile[ty + r][tx] = Wm[(size_t)(k0 + ty + r) * N + n0 + tx];
    __syncthreads();
#pragma unroll
    for (int r = 0; r < 32; r += 8)
        Wt[(size_t)(n0 + ty + r) * K + k0 + tx] = f2b(tile[tx][ty + r]);
}

__global__ void catbias(const float* __restrict__ bq, const float* __restrict__ bk,
                        const float* __restrict__ bv, float* __restrict__ out) {
    int i = blockIdx.x * 256 + threadIdx.x;
    float v = (i < 1024) ? bq[i] : (i < 2048) ? bk[i - 1024] : bv[i - 2048];
    out[i] = v;
}

// ---------------- LayerNorm -> bf16 out ----------------
__global__ void ln_bf16(const float* __restrict__ x, const float* __restrict__ g,
                        const float* __restrict__ b, u16* __restrict__ out) {
    int row = blockIdx.x;
    int t = threadIdx.x;
    const float* xr = x + (size_t)row * D_;
    __shared__ float red[256];

    float s = 0.f;
    for (int i = t; i < D_; i += 256) s += xr[i];
    red[t] = s; __syncthreads();
    for (int off = 128; off > 0; off >>= 1) {
        if (t < off) red[t] += red[t + off];
        __syncthreads();
    }
    float mu = red[0] * (1.0f / D_);
    __syncthreads();

    float vs = 0.f;
    for (int i = t; i < D_; i += 256) { float d = xr[i] - mu; vs += d * d; }
    red[t] = vs; __syncthreads();
    for (int off = 128; off > 0; off >>= 1) {
        if (t < off) red[t] += red[t + off];
        __syncthreads();
    }
    float rstd = rsqrtf(red[0] * (1.0f / D_) + 1e-5f);

    u16* outr = out + (size_t)row * D_;
    for (int i = t; i < D_; i += 256)
        outr[i] = f2b((xr[i] - mu) * rstd * g[i] + b[i]);
}

// ---------------- bf16 MFMA GEMM: C = A[:, koff:koff+K] @ Bt[:, koff:...]^T ------
// blockIdx.x = row-block (XCD-colocates A-row sharers), blockIdx.y = col-block,
// blockIdx.z = K-chunk. BK=64 (two 32-K sub-buffers), XOR-swizzled LDS quarters.
// EPI 0: bf16 QKV scatter; 1: fp32 + residual; 2: bf16 GELU; 3: bf16 raw partial
template <int EPI>
__global__ __launch_bounds__(256)
void gemm_bt(const u16* __restrict__ A, const u16* __restrict__ Bt,
             const float* __restrict__ bias, const float* __restrict__ R,
             void* __restrict__ Cv, int M, int N, int K, int ldA, int ldB) {
    __shared__ u16 As[2 * 128 * 32];
    __shared__ u16 Bs[2 * 128 * 32];
    int tid = threadIdx.x;
    int lane = tid & 63, w = tid >> 6;
    int wm = w >> 1, wn = w & 1;
    int m0 = blockIdx.x * 128, n0 = blockIdx.y * 128;
    size_t koff = (size_t)blockIdx.z * K;

    floatx4 acc[4][4];
#pragma unroll
    for (int a = 0; a < 4; a++)
#pragma unroll
        for (int b2 = 0; b2 < 4; b2++) acc[a][b2] = (floatx4){0.f, 0.f, 0.f, 0.f};

    // staging: lane L covers row (w*16 + L>>2); fetch swizzled logical quarter
    int r4 = lane >> 2;
    int qg = ((lane & 3) ^ ((lane >> 3) & 3)) * 8;
    const u16* Ag0 = A + (size_t)(m0 + w * 16 + r4) * ldA + koff + qg;
    const u16* Bg0 = Bt + (size_t)(n0 + w * 16 + r4) * ldB + koff + qg;
    u16* Al = As + (w * 16) * 32;
    u16* Bl = Bs + (w * 16) * 32;

    // read pointers (iteration-invariant): physical quarter = g ^ ((c>>1)&3)
    int c = lane & 15, g = lane >> 4;
    int sw = (g ^ ((c >> 1) & 3)) * 8;
    const u16* pa[4];
    const u16* pb[4];
#pragma unroll
    for (int a = 0; a < 4; a++) pa[a] = &As[(wm * 64 + a * 16 + c) * 32 + sw];
#pragma unroll
    for (int b2 = 0; b2 < 4; b2++) pb[b2] = &Bs[(wn * 64 + b2 * 16 + c) * 32 + sw];

    for (int k0 = 0; k0 < K; k0 += 64) {
        __syncthreads();
        gl_lds16(Ag0 + k0,                      Al);
        gl_lds16(Ag0 + k0 + (size_t)64 * ldA,   Al + 64 * 32);
        gl_lds16(Ag0 + k0 + 32,                 Al + 128 * 32);
        gl_lds16(Ag0 + k0 + 32 + (size_t)64 * ldA, Al + 192 * 32);
        gl_lds16(Bg0 + k0,                      Bl);
        gl_lds16(Bg0 + k0 + (size_t)64 * ldB,   Bl + 64 * 32);
        gl_lds16(Bg0 + k0 + 32,                 Bl + 128 * 32);
        gl_lds16(Bg0 + k0 + 32 + (size_t)64 * ldB, Bl + 192 * 32);
        __syncthreads();

        short8 fa[4], fb[4];
#pragma unroll
        for (int a = 0; a < 4; a++) fa[a] = *(const short8*)pa[a];
#pragma unroll
        for (int b2 = 0; b2 < 4; b2++) fb[b2] = *(const short8*)pb[b2];
#pragma unroll
        for (int a = 0; a < 4; a++)
#pragma unroll
            for (int b2 = 0; b2 < 4; b2++)
                acc[a][b2] = __builtin_amdgcn_mfma_f32_16x16x32_bf16(fa[a], fb[b2], acc[a][b2], 0, 0, 0);
#pragma unroll
        for (int a = 0; a < 4; a++) fa[a] = *(const short8*)(pa[a] + 128 * 32);
#pragma unroll
        for (int b2 = 0; b2 < 4; b2++) fb[b2] = *(const short8*)(pb[b2] + 128 * 32);
#pragma unroll
        for (int a = 0; a < 4; a++)
#pragma unroll
            for (int b2 = 0; b2 < 4; b2++)
                acc[a][b2] = __builtin_amdgcn_mfma_f32_16x16x32_bf16(fa[a], fb[b2], acc[a][b2], 0, 0, 0);
    }

    int mb = m0 + wm * 64, nb = n0 + wn * 64;
#pragma unroll
    for (int a = 0; a < 4; a++) {
#pragma unroll
        for (int b2 = 0; b2 < 4; b2++) {
            int mrow = mb + a * 16 + (lane >> 4) * 4;
            int ncol = nb + b2 * 16 + (lane & 15);
            float bv = (EPI == 3) ? 0.f : bias[ncol];
#pragma unroll
            for (int r = 0; r < 4; r++) {
                int m = mrow + r;
                float vvv = acc[a][b2][r] + bv;
                if (EPI == 0) {
                    int which = ncol >> 10, col = ncol & 1023;
                    int bb = m >> 11, ss = m & 2047, hh = col >> 6, dk = col & 63;
                    ((u16*)Cv)[(size_t)which * ((size_t)B_ * S_ * D_) +
                               ((((size_t)bb * H_ + hh) * S_) + ss) * DK_ + dk] = f2b(vvv);
                } else if (EPI == 1) {
                    ((float*)Cv)[(size_t)m * N + ncol] = vvv + R[(size_t)m * N + ncol];
                } else if (EPI == 2) {
                    ((u16*)Cv)[(size_t)m * N + ncol] =
                        f2b(0.5f * vvv * (1.f + erff(vvv * 0.70710678118654752f)));
                } else {
                    ((u16*)Cv)[(size_t)blockIdx.z * M * N + (size_t)m * N + ncol] = f2b(vvv);
                }
            }
        }
    }
}

// ---------------- FFN2 split-K merge: out = x1 + bf2 + sum_z P[z] ----------------
__global__ __launch_bounds__(256)
void ffn2_merge(const u16* __restrict__ P, const float* __restrict__ x1,
                const float* __restrict__ bf2, float* __restrict__ out) {
    const size_t MN = (size_t)B_ * S_ * D_;
    int e = (blockIdx.x * 256 + threadIdx.x) * 4;
    float4 xv = *(const float4*)&x1[e];
    float4 bv = *(const float4*)&bf2[e & 1023];
    float o0 = xv.x + bv.x, o1 = xv.y + bv.y, o2 = xv.z + bv.z, o3 = xv.w + bv.w;
#pragma unroll
    for (int z = 0; z < 4; z++) {
        ushort4_t pv = *(const ushort4_t*)&P[z * MN + e];
        o0 += b2f(pv[0]); o1 += b2f(pv[1]); o2 += b2f(pv[2]); o3 += b2f(pv[3]);
    }
    *(float4*)&out[e] = (float4){o0, o1, o2, o3};
}

// ---------------- MFMA sparse strided attention: block = (b,h, 64 queries) --------
__global__ __launch_bounds__(256)
void attn3(const u16* __restrict__ q, const u16* __restrict__ k,
           const u16* __restrict__ v, const int* __restrict__ mask,
           u16* __restrict__ ob) {
    __shared__ u16 Qs[64 * 72];
    __shared__ u16 Kw[192 * 72];
    __shared__ u16 Vt[64 * 200];
    __shared__ u16 Vband[4][16 * 64];
    __shared__ float sb[64][17];

    const int i0 = blockIdx.x * 64;
    const int bh = blockIdx.y;
    const int b  = bh >> 4, h = bh & 15;
    const int t  = threadIdx.x;
    const int lane = t & 63, w = t >> 6;
    const int c = lane & 15, g = lane >> 4;
    const int qloc16 = w * 16;

    const u16* qg = q + ((size_t)bh * S_ + i0) * DK_;
    const u16* kg = k + (size_t)bh * S_ * DK_;
    const u16* vg = v + (size_t)bh * S_ * DK_;

    const int wlo = (i0 >= 128) ? i0 - 128 : 0;
    const int wn  = i0 + 64 - wlo;
    const int nb  = (i0 >= 256) ? (i0 >> 7) - 1 : 0;
    const int jb0 = i0 & 127;
    const int dd0 = i0 - wlo;

    for (int e = t; e < 64 * 8; e += 256) {
        int row = e >> 3, dc = e & 7;
        *(short8*)&Qs[row * 72 + dc * 8] = *(const short8*)(qg + row * 64 + dc * 8);
    }
    for (int e = t; e < wn * 8; e += 256) {
        int row = e >> 3, dc = e & 7;
        *(short8*)&Kw[row * 72 + dc * 8] = *(const short8*)(kg + (size_t)(wlo + row) * 64 + dc * 8);
    }
#pragma unroll
    for (int dc = 0; dc < 8; dc++) {
        for (int jl = t; jl < 192; jl += 256) {
            short8 val = {0, 0, 0, 0, 0, 0, 0, 0};
            if (jl < wn) val = *(const short8*)(vg + (size_t)(wlo + jl) * 64 + dc * 8);
#pragma unroll
            for (int i = 0; i < 8; i++) Vt[(dc * 8 + i) * 200 + jl] = (u16)val[i];
        }
    }
    __syncthreads();

    for (int m = 0; m < nb; m++) {
        int jb = jb0 + (m << 7);
        int jrow = jb + qloc16 + c;
        float p = 0.f;
#pragma unroll
        for (int kc = 0; kc < 2; kc++) {
            short8 kv = *(const short8*)(kg + (size_t)jrow * 64 + kc * 32 + g * 8);
            short8 qv = *(const short8*)&Qs[(qloc16 + c) * 72 + kc * 32 + g * 8];
#pragma unroll
            for (int i = 0; i < 8; i++) p += b2f((u16)qv[i]) * b2f((u16)kv[i]);
        }
        p += __shfl_xor(p, 16);
        p += __shfl_xor(p, 32);
        if (g == 0) {
            int qi = i0 + qloc16 + c;
            float s = p * 0.125f;
            if (mask[(size_t)qi * S_ + jrow] == 0) s = NEG_;
            sb[qloc16 + c][m] = s;
        }
    }

    floatx4 sc[12];
#pragma unroll
    for (int ct = 0; ct < 12; ct++) sc[ct] = (floatx4){0.f, 0.f, 0.f, 0.f};
    short8 fa0 = *(const short8*)&Qs[(qloc16 + c) * 72 + g * 8];
    short8 fa1 = *(const short8*)&Qs[(qloc16 + c) * 72 + 32 + g * 8];
#pragma unroll
    for (int ct = 0; ct < 12; ct++) {
        short8 fb0 = *(const short8*)&Kw[(ct * 16 + c) * 72 + g * 8];
        short8 fb1 = *(const short8*)&Kw[(ct * 16 + c) * 72 + 32 + g * 8];
        sc[ct] = __builtin_amdgcn_mfma_f32_16x16x32_bf16(fa0, fb0, sc[ct], 0, 0, 0);
        sc[ct] = __builtin_amdgcn_mfma_f32_16x16x32_bf16(fa1, fb1, sc[ct], 0, 0, 0);
    }

#pragma unroll
    for (int ct = 0; ct < 12; ct++) {
        int cidx = ct * 16 + c;
        int j = wlo + cidx;
#pragma unroll
        for (int r = 0; r < 4; r++) {
            int qloc = qloc16 + g * 4 + r;
            int d = dd0 + qloc - cidx;
            float s = sc[ct][r] * 0.125f;
            bool ok = false;
            if (d >= 0 && d <= 128) ok = (mask[(size_t)(i0 + qloc) * S_ + j] != 0);
            sc[ct][r] = ok ? s : NEG_;
        }
    }

    float mv[4], inv[4];
#pragma unroll
    for (int r = 0; r < 4; r++) {
        float mm = -1e30f;
#pragma unroll
        for (int ct = 0; ct < 12; ct++) mm = fmaxf(mm, sc[ct][r]);
        mm = fmaxf(mm, __shfl_xor(mm, 1));
        mm = fmaxf(mm, __shfl_xor(mm, 2));
        mm = fmaxf(mm, __shfl_xor(mm, 4));
        mm = fmaxf(mm, __shfl_xor(mm, 8));
        int qloc = qloc16 + g * 4 + r;
        for (int m = 0; m < nb; m++) mm = fmaxf(mm, sb[qloc][m]);
        float sum = 0.f;
#pragma unroll
        for (int ct = 0; ct < 12; ct++) {
            float e = __expf(sc[ct][r] - mm);
            sc[ct][r] = e;
            sum += e;
        }
        sum += __shfl_xor(sum, 1);
        sum += __shfl_xor(sum, 2);
        sum += __shfl_xor(sum, 4);
        sum += __shfl_xor(sum, 8);
        for (int m = 0; m < nb; m++) sum += __expf(sb[qloc][m] - mm);
        mv[r] = mm;
        inv[r] = 1.f / sum;
    }

    __syncthreads();
    u16* P = Kw;
#pragma unroll
    for (int ct = 0; ct < 12; ct++) {
#pragma unroll
        for (int r = 0; r < 4; r++) {
            int qloc = qloc16 + g * 4 + r;
            P[qloc * 200 + ct * 16 + c] = f2b(sc[ct][r]);
        }
    }

    floatx4 o[4];
#pragma unroll
    for (int nt = 0; nt < 4; nt++) o[nt] = (floatx4){0.f, 0.f, 0.f, 0.f};
#pragma unroll
    for (int ks = 0; ks < 6; ks++) {
        short8 pa = *(const short8*)&P[(qloc16 + c) * 200 + ks * 32 + g * 8];
#pragma unroll
        for (int nt = 0; nt < 4; nt++) {
            short8 vb = *(const short8*)&Vt[(nt * 16 + c) * 200 + ks * 32 + g * 8];
            o[nt] = __builtin_amdgcn_mfma_f32_16x16x32_bf16(pa, vb, o[nt], 0, 0, 0);
        }
    }

    for (int m = 0; m < nb; m++) {
        int jb = jb0 + (m << 7);
        asm volatile("s_waitcnt lgkmcnt(0)" ::: "memory");
        __builtin_amdgcn_wave_barrier();
        gl_lds16(vg + (size_t)(jb + qloc16 + (lane >> 3)) * 64 + (lane & 7) * 8, &Vband[w][0]);
        gl_lds16(vg + (size_t)(jb + qloc16 + 8 + (lane >> 3)) * 64 + (lane & 7) * 8, &Vband[w][512]);
        asm volatile("s_waitcnt vmcnt(0)" ::: "memory");
        __builtin_amdgcn_wave_barrier();
#pragma unroll
        for (int r = 0; r < 4; r++) {
            int qloc = qloc16 + g * 4 + r;
            float pb = __expf(sb[qloc][m] - mv[r]);
#pragma unroll
            for (int nt = 0; nt < 4; nt++)
                o[nt][r] += pb * b2f(Vband[w][(g * 4 + r) * 64 + nt * 16 + c]);
        }
    }

#pragma unroll
    for (int nt = 0; nt < 4; nt++) {
#pragma unroll
        for (int r = 0; r < 4; r++) {
            int qi = i0 + qloc16 + g * 4 + r;
            ob[((size_t)b * S_ + qi) * D_ + h * 64 + nt * 16 + c] = f2b(o[nt][r] * inv[r]);
        }
    }
}

extern "C" void kernel_launch(void* const* d_in, const int* in_sizes, int n_in,
                              void* d_out, int out_size, void* d_ws, size_t ws_size,
                              hipStream_t stream) {
    const float* x    = (const float*)d_in[0];
    const int*   mask = (const int*)  d_in[1];
    const float* Wq   = (const float*)d_in[2];
    const float* bq   = (const float*)d_in[3];
    const float* Wk   = (const float*)d_in[4];
    const float* bk   = (const float*)d_in[5];
    const float* Wv   = (const float*)d_in[6];
    const float* bv   = (const float*)d_in[7];
    const float* Wo   = (const float*)d_in[8];
    const float* bo   = (const float*)d_in[9];
    const float* W1   = (const float*)d_in[10];
    const float* bf1  = (const float*)d_in[11];
    const float* W2   = (const float*)d_in[12];
    const float* bf2  = (const float*)d_in[13];
    const float* g1   = (const float*)d_in[14];
    const float* bl1  = (const float*)d_in[15];
    const float* g2   = (const float*)d_in[16];
    const float* bl2  = (const float*)d_in[17];

    char* wsb = (char*)d_ws;
    const size_t MB = 1024 * 1024;
    u16*   WtQKV = (u16*)(wsb + 0);          // 6 MB; WtO contiguous after (tconv4 dst)
    u16*   WtO   = (u16*)(wsb + 6 * MB);     // 2 MB
    u16*   Wt1   = (u16*)(wsb + 8 * MB);     // 8 MB
    u16*   Wt2   = (u16*)(wsb + 16 * MB);    // 8 MB
    u16*   n1b   = (u16*)(wsb + 24 * MB);    // 8 MB (reused as n2b)
    u16*   qkv   = (u16*)(wsb + 32 * MB);    // 24 MB (dead after attn)
    u16*   obb   = (u16*)(wsb + 56 * MB);    // 8 MB (dead after Wo gemm)
    float* x1    = (float*)(wsb + 32 * MB);  // 16 MB over dead q|k (live thru merge)
    u16*   ff1b  = (u16*)(wsb + 48 * MB);    // 33.5 MB over dead v|obb
    u16*   Ppart = (u16*)(wsb + 82 * MB);    // 32 MB: 4 x bf16 partials
    float* bcat  = (float*)(wsb + 114 * MB); // 12 KB
    u16*   n2b   = n1b;

    const int M = B_ * S_;  // 4096
    const size_t SZ = (size_t)B_ * S_ * D_;

    // 0. weight transpose + convert, bias concat
    tconv4<<<dim3(32, 32, 4), 256, 0, stream>>>(Wq, Wk, Wv, Wo, WtQKV);
    tconv<<<dim3(128, 32), 256, 0, stream>>>(W1, Wt1, 1024, 4096);
    tconv<<<dim3(32, 128), 256, 0, stream>>>(W2, Wt2, 4096, 1024);
    catbias<<<12, 256, 0, stream>>>(bq, bk, bv, bcat);

    // 1. LN1 -> bf16
    ln_bf16<<<M, 256, 0, stream>>>(x, g1, bl1, n1b);

    // 2. fused QKV projection (N=3072) -> bf16 [B,H,S,DK] x3
    gemm_bt<0><<<dim3(32, 24), 256, 0, stream>>>(n1b, WtQKV, bcat, nullptr, qkv,
                                                 M, 3072, 1024, 1024, 1024);

    // 3. sparse strided attention (MFMA) -> bf16 [B,S,D]
    attn3<<<dim3(32, 32), 256, 0, stream>>>(qkv, qkv + SZ, qkv + 2 * SZ, mask, obb);

    // 4. x1 = x + ob @ Wo + bo (fp32)
    gemm_bt<1><<<dim3(32, 8), 256, 0, stream>>>(obb, WtO, bo, x, x1,
                                                M, 1024, 1024, 1024, 1024);

    // 5. LN2 -> bf16
    ln_bf16<<<M, 256, 0, stream>>>(x1, g2, bl2, n2b);

    // 6. ff1 = GELU(n2 @ W1 + bf1) -> bf16
    gemm_bt<2><<<dim3(32, 32), 256, 0, stream>>>(n2b, Wt1, bf1, nullptr, ff1b,
                                                 M, 4096, 1024, 1024, 1024);

    // 7. FFN2 split-K=4: partials -> merge (out = x1 + ff1 @ W2 + bf2)
    gemm_bt<3><<<dim3(32, 8, 4), 256, 0, stream>>>(ff1b, Wt2, nullptr, nullptr, Ppart,
                                                   M, 1024, 1024, 4096, 4096);
    ffn2_merge<<<(int)(SZ / 1024), 256, 0, stream>>>(Ppart, x1, bf2, (float*)d_out);
}

// Round 5
// 404.683 us; speedup vs baseline: 6.6223x; 1.1053x over previous
//
#include <hip/hip_runtime.h>
#include <math.h>

typedef unsigned int u32;
typedef unsigned short u16;

#define B_  2
#define S_  2048
#define D_  1024
#define H_  16
#define DK_ 64
#define FF_ 4096
#define NEG_ -1000000000.0f

typedef __attribute__((ext_vector_type(8))) short short8;
typedef __attribute__((ext_vector_type(4))) float floatx4;
typedef __attribute__((ext_vector_type(4))) unsigned short ushort4_t;

__device__ inline u16 f2b(float f) {
    union { float f; u32 u; } v; v.f = f;
    u32 r = (v.u + 0x7fffu + ((v.u >> 16) & 1u)) >> 16;
    return (u16)r;
}
__device__ inline float b2f(u16 b) {
    union { u32 u; float f; } v; v.u = ((u32)b) << 16;
    return v.f;
}

__device__ inline void gl_lds16(const u16* g, u16* l) {
    __builtin_amdgcn_global_load_lds((const __attribute__((address_space(1))) u32*)g,
                                     (__attribute__((address_space(3))) u32*)l, 16, 0, 0);
}

// ------- 4x square (1024x1024) weight transpose+convert in one launch -------
__global__ void tconv4(const float* __restrict__ W0, const float* __restrict__ W1_,
                       const float* __restrict__ W2_, const float* __restrict__ W3,
                       u16* __restrict__ dstBase) {
    __shared__ float tile[32][33];
    int z = blockIdx.z;
    const float* Wm = (z == 0) ? W0 : (z == 1) ? W1_ : (z == 2) ? W2_ : W3;
    u16* Wt = dstBase + (size_t)z * 1024 * 1024;
    const int K = 1024, N = 1024;
    int n0 = blockIdx.x * 32, k0 = blockIdx.y * 32;
    int tx = threadIdx.x & 31, ty = threadIdx.x >> 5;
#pragma unroll
    for (int r = 0; r < 32; r += 8)
        tile[ty + r][tx] = Wm[(size_t)(k0 + ty + r) * N + n0 + tx];
    __syncthreads();
#pragma unroll
    for (int r = 0; r < 32; r += 8)
        Wt[(size_t)(n0 + ty + r) * K + k0 + tx] = f2b(tile[tx][ty + r]);
}

__global__ void tconv(const float* __restrict__ Wm, u16* __restrict__ Wt, int K, int N) {
    __shared__ float tile[32][33];
    int n0 = blockIdx.x * 32, k0 = blockIdx.y * 32;
    int tx = threadIdx.x & 31, ty = threadIdx.x >> 5;
#pragma unroll
    for (int r = 0; r < 32; r += 8)
        tile[ty + r][tx] = Wm[(size_t)(k0 + ty + r) * N + n0 + tx];
    __syncthreads();
#pragma unroll
    for (int r = 0; r < 32; r += 8)
        Wt[(size_t)(n0 + ty + r) * K + k0 + tx] = f2b(tile[tx][ty + r]);
}

__global__ void catbias(const float* __restrict__ bq, const float* __restrict__ bk,
                        const float* __restrict__ bv, float* __restrict__ out) {
    int i = blockIdx.x * 256 + threadIdx.x;
    float v = (i < 1024) ? bq[i] : (i < 2048) ? bk[i - 1024] : bv[i - 2048];
    out[i] = v;
}

// ---------------- LayerNorm -> bf16 out ----------------
__global__ void ln_bf16(const float* __restrict__ x, const float* __restrict__ g,
                        const float* __restrict__ b, u16* __restrict__ out) {
    int row = blockIdx.x;
    int t = threadIdx.x;
    const float* xr = x + (size_t)row * D_;
    __shared__ float red[256];

    float v[4];
    float s = 0.f;
#pragma unroll
    for (int i = 0; i < 4; i++) { v[i] = xr[i * 256 + t]; s += v[i]; }
    red[t] = s; __syncthreads();
    for (int off = 128; off > 0; off >>= 1) {
        if (t < off) red[t] += red[t + off];
        __syncthreads();
    }
    float mu = red[0] * (1.0f / D_);
    __syncthreads();

    float vs = 0.f;
#pragma unroll
    for (int i = 0; i < 4; i++) { float d = v[i] - mu; vs += d * d; }
    red[t] = vs; __syncthreads();
    for (int off = 128; off > 0; off >>= 1) {
        if (t < off) red[t] += red[t + off];
        __syncthreads();
    }
    float rstd = rsqrtf(red[0] * (1.0f / D_) + 1e-5f);

    u16* outr = out + (size_t)row * D_;
#pragma unroll
    for (int i = 0; i < 4; i++) {
        int col = i * 256 + t;
        outr[col] = f2b((v[i] - mu) * rstd * g[col] + b[col]);
    }
}

// ---- fused split-K merge + residual + bias + LayerNorm (for Wo path) ----
// x1 = x + bo + P[0] + P[1];  n2 = LN(x1; g2, bl2)
__global__ __launch_bounds__(256)
void merge_ln(const u16* __restrict__ P, const float* __restrict__ x,
              const float* __restrict__ bo, const float* __restrict__ g,
              const float* __restrict__ bl, float* __restrict__ x1,
              u16* __restrict__ n2) {
    const size_t MN = (size_t)B_ * S_ * D_;
    int row = blockIdx.x, t = threadIdx.x;
    size_t base = (size_t)row * D_;
    __shared__ float red[256];

    float v[4];
    float s = 0.f;
#pragma unroll
    for (int i = 0; i < 4; i++) {
        int col = i * 256 + t;
        float val = x[base + col] + bo[col] + b2f(P[base + col]) + b2f(P[MN + base + col]);
        v[i] = val; s += val;
    }
    red[t] = s; __syncthreads();
    for (int off = 128; off > 0; off >>= 1) {
        if (t < off) red[t] += red[t + off];
        __syncthreads();
    }
    float mu = red[0] * (1.0f / D_);
    __syncthreads();

    float vs = 0.f;
#pragma unroll
    for (int i = 0; i < 4; i++) { float d = v[i] - mu; vs += d * d; }
    red[t] = vs; __syncthreads();
    for (int off = 128; off > 0; off >>= 1) {
        if (t < off) red[t] += red[t + off];
        __syncthreads();
    }
    float rstd = rsqrtf(red[0] * (1.0f / D_) + 1e-5f);

#pragma unroll
    for (int i = 0; i < 4; i++) {
        int col = i * 256 + t;
        x1[base + col] = v[i];
        n2[base + col] = f2b((v[i] - mu) * rstd * g[col] + bl[col]);
    }
}

// ---------------- bf16 MFMA GEMM, cross-iteration prefetch double-buffer ---------
// C = A[:, koff:koff+K] @ Bt[:, koff:koff+K]^T (+epilogue). BK=32, 2x16KB LDS bufs,
// ONE barrier per iter; next tile's global_load_lds issued right after the barrier
// so the following barrier's vmcnt drain is covered by this iter's compute.
// EPI 0: bf16 QKV scatter; 1: fp32 + residual; 2: bf16 GELU(tanh); 3: bf16 partial
template <int EPI>
__global__ __launch_bounds__(256, 4)
void gemm_bt(const u16* __restrict__ A, const u16* __restrict__ Bt,
             const float* __restrict__ bias, const float* __restrict__ R,
             void* __restrict__ Cv, int M, int N, int K, int ldA, int ldB) {
    __shared__ u16 As[2][128 * 32];
    __shared__ u16 Bs[2][128 * 32];
    int tid = threadIdx.x;
    int lane = tid & 63, w = tid >> 6;
    int wm = w >> 1, wn = w & 1;
    int m0 = blockIdx.x * 128, n0 = blockIdx.y * 128;
    size_t koff = (size_t)blockIdx.z * K;

    floatx4 acc[4][4];
#pragma unroll
    for (int a = 0; a < 4; a++)
#pragma unroll
        for (int b2 = 0; b2 < 4; b2++) acc[a][b2] = (floatx4){0.f, 0.f, 0.f, 0.f};

    // staging: lane L covers row (w*16 + L>>2), fetches swizzled logical quarter
    int r4 = lane >> 2;
    int qg = ((lane & 3) ^ ((lane >> 3) & 3)) * 8;
    const u16* Ag0 = A + (size_t)(m0 + w * 16 + r4) * ldA + koff + qg;
    const u16* Bg0 = Bt + (size_t)(n0 + w * 16 + r4) * ldB + koff + qg;
    const int ldsOff = (w * 16) * 32;

    // read side: physical quarter = g ^ ((row&15)>>1 & 3); row&15 == c
    int c = lane & 15, g = lane >> 4;
    int sw = (g ^ ((c >> 1) & 3)) * 8;

    const int nIter = K >> 5;

    // prologue: stage tile 0 into buf 0
    gl_lds16(Ag0, &As[0][ldsOff]);
    gl_lds16(Ag0 + (size_t)64 * ldA, &As[0][ldsOff + 64 * 32]);
    gl_lds16(Bg0, &Bs[0][ldsOff]);
    gl_lds16(Bg0 + (size_t)64 * ldB, &Bs[0][ldsOff + 64 * 32]);

    for (int it = 0; it < nIter; it++) {
        __syncthreads();  // drains prefetch of buf[cur]; readers of buf[nxt] done
        int cur = it & 1, nxt = cur ^ 1;
        if (it + 1 < nIter) {
            int kk = (it + 1) << 5;
            gl_lds16(Ag0 + kk, &As[nxt][ldsOff]);
            gl_lds16(Ag0 + kk + (size_t)64 * ldA, &As[nxt][ldsOff + 64 * 32]);
            gl_lds16(Bg0 + kk, &Bs[nxt][ldsOff]);
            gl_lds16(Bg0 + kk + (size_t)64 * ldB, &Bs[nxt][ldsOff + 64 * 32]);
        }
        short8 fa[4], fb[4];
#pragma unroll
        for (int a = 0; a < 4; a++)
            fa[a] = *(const short8*)&As[cur][(wm * 64 + a * 16 + c) * 32 + sw];
#pragma unroll
        for (int b2 = 0; b2 < 4; b2++)
            fb[b2] = *(const short8*)&Bs[cur][(wn * 64 + b2 * 16 + c) * 32 + sw];
#pragma unroll
        for (int a = 0; a < 4; a++)
#pragma unroll
            for (int b2 = 0; b2 < 4; b2++)
                acc[a][b2] = __builtin_amdgcn_mfma_f32_16x16x32_bf16(fa[a], fb[b2], acc[a][b2], 0, 0, 0);
    }

    int mb = m0 + wm * 64, nb = n0 + wn * 64;
#pragma unroll
    for (int a = 0; a < 4; a++) {
#pragma unroll
        for (int b2 = 0; b2 < 4; b2++) {
            int mrow = mb + a * 16 + g * 4;
            int ncol = nb + b2 * 16 + c;
            float bv = (EPI == 3) ? 0.f : bias[ncol];
#pragma unroll
            for (int r = 0; r < 4; r++) {
                int m = mrow + r;
                float vvv = acc[a][b2][r] + bv;
                if (EPI == 0) {
                    int which = ncol >> 10, col = ncol & 1023;
                    int bb = m >> 11, ss = m & 2047, hh = col >> 6, dk = col & 63;
                    ((u16*)Cv)[(size_t)which * ((size_t)B_ * S_ * D_) +
                               ((((size_t)bb * H_ + hh) * S_) + ss) * DK_ + dk] = f2b(vvv);
                } else if (EPI == 1) {
                    ((float*)Cv)[(size_t)m * N + ncol] = vvv + R[(size_t)m * N + ncol];
                } else if (EPI == 2) {
                    // GELU, tanh form (max dev ~2e-3 vs exact erf)
                    float u = 0.79788456080286536f * fmaf(0.044715f * vvv, vvv * vvv, vvv);
                    float th = 1.f - 2.f / (1.f + __expf(2.f * u));
                    ((u16*)Cv)[(size_t)m * N + ncol] = f2b(0.5f * vvv * (1.f + th));
                } else {
                    ((u16*)Cv)[(size_t)blockIdx.z * M * N + (size_t)m * N + ncol] = f2b(vvv);
                }
            }
        }
    }
}

// ---------------- FFN2 split-K merge: out = x1 + bf2 + sum_z P[z] ----------------
__global__ __launch_bounds__(256)
void ffn2_merge(const u16* __restrict__ P, const float* __restrict__ x1,
                const float* __restrict__ bf2, float* __restrict__ out) {
    const size_t MN = (size_t)B_ * S_ * D_;
    int e = (blockIdx.x * 256 + threadIdx.x) * 4;
    float4 xv = *(const float4*)&x1[e];
    float4 bv = *(const float4*)&bf2[e & 1023];
    float o0 = xv.x + bv.x, o1 = xv.y + bv.y, o2 = xv.z + bv.z, o3 = xv.w + bv.w;
#pragma unroll
    for (int z = 0; z < 4; z++) {
        ushort4_t pv = *(const ushort4_t*)&P[z * MN + e];
        o0 += b2f(pv[0]); o1 += b2f(pv[1]); o2 += b2f(pv[2]); o3 += b2f(pv[3]);
    }
    *(float4*)&out[e] = (float4){o0, o1, o2, o3};
}

// ---------------- MFMA sparse strided attention: block = (b,h, 64 queries) --------
__global__ __launch_bounds__(256)
void attn3(const u16* __restrict__ q, const u16* __restrict__ k,
           const u16* __restrict__ v, const int* __restrict__ mask,
           u16* __restrict__ ob) {
    __shared__ u16 Qs[64 * 72];
    __shared__ u16 Kw[192 * 72];
    __shared__ u16 Vt[64 * 200];
    __shared__ u16 Vband[4][16 * 64];
    __shared__ float sb[64][17];

    const int i0 = blockIdx.x * 64;
    const int bh = blockIdx.y;
    const int b  = bh >> 4, h = bh & 15;
    const int t  = threadIdx.x;
    const int lane = t & 63, w = t >> 6;
    const int c = lane & 15, g = lane >> 4;
    const int qloc16 = w * 16;

    const u16* qg = q + ((size_t)bh * S_ + i0) * DK_;
    const u16* kg = k + (size_t)bh * S_ * DK_;
    const u16* vg = v + (size_t)bh * S_ * DK_;

    const int wlo = (i0 >= 128) ? i0 - 128 : 0;
    const int wn  = i0 + 64 - wlo;
    const int nb  = (i0 >= 256) ? (i0 >> 7) - 1 : 0;
    const int jb0 = i0 & 127;
    const int dd0 = i0 - wlo;

    for (int e = t; e < 64 * 8; e += 256) {
        int row = e >> 3, dc = e & 7;
        *(short8*)&Qs[row * 72 + dc * 8] = *(const short8*)(qg + row * 64 + dc * 8);
    }
    for (int e = t; e < wn * 8; e += 256) {
        int row = e >> 3, dc = e & 7;
        *(short8*)&Kw[row * 72 + dc * 8] = *(const short8*)(kg + (size_t)(wlo + row) * 64 + dc * 8);
    }
#pragma unroll
    for (int dc = 0; dc < 8; dc++) {
        for (int jl = t; jl < 192; jl += 256) {
            short8 val = {0, 0, 0, 0, 0, 0, 0, 0};
            if (jl < wn) val = *(const short8*)(vg + (size_t)(wlo + jl) * 64 + dc * 8);
#pragma unroll
            for (int i = 0; i < 8; i++) Vt[(dc * 8 + i) * 200 + jl] = (u16)val[i];
        }
    }
    __syncthreads();

    for (int m = 0; m < nb; m++) {
        int jb = jb0 + (m << 7);
        int jrow = jb + qloc16 + c;
        float p = 0.f;
#pragma unroll
        for (int kc = 0; kc < 2; kc++) {
            short8 kv = *(const short8*)(kg + (size_t)jrow * 64 + kc * 32 + g * 8);
            short8 qv = *(const short8*)&Qs[(qloc16 + c) * 72 + kc * 32 + g * 8];
#pragma unroll
            for (int i = 0; i < 8; i++) p += b2f((u16)qv[i]) * b2f((u16)kv[i]);
        }
        p += __shfl_xor(p, 16);
        p += __shfl_xor(p, 32);
        if (g == 0) {
            int qi = i0 + qloc16 + c;
            float s = p * 0.125f;
            if (mask[(size_t)qi * S_ + jrow] == 0) s = NEG_;
            sb[qloc16 + c][m] = s;
        }
    }

    floatx4 sc[12];
#pragma unroll
    for (int ct = 0; ct < 12; ct++) sc[ct] = (floatx4){0.f, 0.f, 0.f, 0.f};
    short8 fa0 = *(const short8*)&Qs[(qloc16 + c) * 72 + g * 8];
    short8 fa1 = *(const short8*)&Qs[(qloc16 + c) * 72 + 32 + g * 8];
#pragma unroll
    for (int ct = 0; ct < 12; ct++) {
        short8 fb0 = *(const short8*)&Kw[(ct * 16 + c) * 72 + g * 8];
        short8 fb1 = *(const short8*)&Kw[(ct * 16 + c) * 72 + 32 + g * 8];
        sc[ct] = __builtin_amdgcn_mfma_f32_16x16x32_bf16(fa0, fb0, sc[ct], 0, 0, 0);
        sc[ct] = __builtin_amdgcn_mfma_f32_16x16x32_bf16(fa1, fb1, sc[ct], 0, 0, 0);
    }

#pragma unroll
    for (int ct = 0; ct < 12; ct++) {
        int cidx = ct * 16 + c;
        int j = wlo + cidx;
#pragma unroll
        for (int r = 0; r < 4; r++) {
            int qloc = qloc16 + g * 4 + r;
            int d = dd0 + qloc - cidx;
            float s = sc[ct][r] * 0.125f;
            bool ok = false;
            if (d >= 0 && d <= 128) ok = (mask[(size_t)(i0 + qloc) * S_ + j] != 0);
            sc[ct][r] = ok ? s : NEG_;
        }
    }

    float mv[4], inv[4];
#pragma unroll
    for (int r = 0; r < 4; r++) {
        float mm = -1e30f;
#pragma unroll
        for (int ct = 0; ct < 12; ct++) mm = fmaxf(mm, sc[ct][r]);
        mm = fmaxf(mm, __shfl_xor(mm, 1));
        mm = fmaxf(mm, __shfl_xor(mm, 2));
        mm = fmaxf(mm, __shfl_xor(mm, 4));
        mm = fmaxf(mm, __shfl_xor(mm, 8));
        int qloc = qloc16 + g * 4 + r;
        for (int m = 0; m < nb; m++) mm = fmaxf(mm, sb[qloc][m]);
        float sum = 0.f;
#pragma unroll
        for (int ct = 0; ct < 12; ct++) {
            float e = __expf(sc[ct][r] - mm);
            sc[ct][r] = e;
            sum += e;
        }
        sum += __shfl_xor(sum, 1);
        sum += __shfl_xor(sum, 2);
        sum += __shfl_xor(sum, 4);
        sum += __shfl_xor(sum, 8);
        for (int m = 0; m < nb; m++) sum += __expf(sb[qloc][m] - mm);
        mv[r] = mm;
        inv[r] = 1.f / sum;
    }

    __syncthreads();
    u16* P = Kw;
#pragma unroll
    for (int ct = 0; ct < 12; ct++) {
#pragma unroll
        for (int r = 0; r < 4; r++) {
            int qloc = qloc16 + g * 4 + r;
            P[qloc * 200 + ct * 16 + c] = f2b(sc[ct][r]);
        }
    }

    floatx4 o[4];
#pragma unroll
    for (int nt = 0; nt < 4; nt++) o[nt] = (floatx4){0.f, 0.f, 0.f, 0.f};
#pragma unroll
    for (int ks = 0; ks < 6; ks++) {
        short8 pa = *(const short8*)&P[(qloc16 + c) * 200 + ks * 32 + g * 8];
#pragma unroll
        for (int nt = 0; nt < 4; nt++) {
            short8 vb = *(const short8*)&Vt[(nt * 16 + c) * 200 + ks * 32 + g * 8];
            o[nt] = __builtin_amdgcn_mfma_f32_16x16x32_bf16(pa, vb, o[nt], 0, 0, 0);
        }
    }

    for (int m = 0; m < nb; m++) {
        int jb = jb0 + (m << 7);
        asm volatile("s_waitcnt lgkmcnt(0)" ::: "memory");
        __builtin_amdgcn_wave_barrier();
        gl_lds16(vg + (size_t)(jb + qloc16 + (lane >> 3)) * 64 + (lane & 7) * 8, &Vband[w][0]);
        gl_lds16(vg + (size_t)(jb + qloc16 + 8 + (lane >> 3)) * 64 + (lane & 7) * 8, &Vband[w][512]);
        asm volatile("s_waitcnt vmcnt(0)" ::: "memory");
        __builtin_amdgcn_wave_barrier();
#pragma unroll
        for (int r = 0; r < 4; r++) {
            int qloc = qloc16 + g * 4 + r;
            float pb = __expf(sb[qloc][m] - mv[r]);
#pragma unroll
            for (int nt = 0; nt < 4; nt++)
                o[nt][r] += pb * b2f(Vband[w][(g * 4 + r) * 64 + nt * 16 + c]);
        }
    }

#pragma unroll
    for (int nt = 0; nt < 4; nt++) {
#pragma unroll
        for (int r = 0; r < 4; r++) {
            int qi = i0 + qloc16 + g * 4 + r;
            ob[((size_t)b * S_ + qi) * D_ + h * 64 + nt * 16 + c] = f2b(o[nt][r] * inv[r]);
        }
    }
}

extern "C" void kernel_launch(void* const* d_in, const int* in_sizes, int n_in,
                              void* d_out, int out_size, void* d_ws, size_t ws_size,
                              hipStream_t stream) {
    const float* x    = (const float*)d_in[0];
    const int*   mask = (const int*)  d_in[1];
    const float* Wq   = (const float*)d_in[2];
    const float* bq   = (const float*)d_in[3];
    const float* Wk   = (const float*)d_in[4];
    const float* bk   = (const float*)d_in[5];
    const float* Wv   = (const float*)d_in[6];
    const float* bv   = (const float*)d_in[7];
    const float* Wo   = (const float*)d_in[8];
    const float* bo   = (const float*)d_in[9];
    const float* W1   = (const float*)d_in[10];
    const float* bf1  = (const float*)d_in[11];
    const float* W2   = (const float*)d_in[12];
    const float* bf2  = (const float*)d_in[13];
    const float* g1   = (const float*)d_in[14];
    const float* bl1  = (const float*)d_in[15];
    const float* g2   = (const float*)d_in[16];
    const float* bl2  = (const float*)d_in[17];

    char* wsb = (char*)d_ws;
    const size_t MB = 1024 * 1024;
    u16*   WtQKV  = (u16*)(wsb + 0);          // 6 MB; WtO contiguous after
    u16*   WtO    = (u16*)(wsb + 6 * MB);     // 2 MB
    u16*   Wt1    = (u16*)(wsb + 8 * MB);     // 8 MB
    u16*   Wt2    = (u16*)(wsb + 16 * MB);    // 8 MB
    u16*   n1b    = (u16*)(wsb + 24 * MB);    // 8 MB (reused as n2b)
    u16*   qkv    = (u16*)(wsb + 32 * MB);    // 24 MB (dead after attn)
    u16*   obb    = (u16*)(wsb + 56 * MB);    // 8 MB (dead after Wo gemm)
    float* x1     = (float*)(wsb + 32 * MB);  // 16 MB over dead q|k (live thru merge)
    u16*   ff1b   = (u16*)(wsb + 48 * MB);    // 33.5 MB over dead v|obb
    u16*   Ppart  = (u16*)(wsb + 82 * MB);    // 32 MB: FFN2 4x bf16 partials
    u16*   PpartO = (u16*)(wsb + 82 * MB);    // 16 MB: Wo 2x partials (dead before FFN2)
    float* bcat   = (float*)(wsb + 114 * MB); // 12 KB
    u16*   n2b    = n1b;

    const int M = B_ * S_;  // 4096
    const size_t SZ = (size_t)B_ * S_ * D_;

    // 0. weight transpose + convert, bias concat
    tconv4<<<dim3(32, 32, 4), 256, 0, stream>>>(Wq, Wk, Wv, Wo, WtQKV);
    tconv<<<dim3(128, 32), 256, 0, stream>>>(W1, Wt1, 1024, 4096);
    tconv<<<dim3(32, 128), 256, 0, stream>>>(W2, Wt2, 4096, 1024);
    catbias<<<12, 256, 0, stream>>>(bq, bk, bv, bcat);

    // 1. LN1 -> bf16
    ln_bf16<<<M, 256, 0, stream>>>(x, g1, bl1, n1b);

    // 2. fused QKV projection (N=3072) -> bf16 [B,H,S,DK] x3
    gemm_bt<0><<<dim3(32, 24), 256, 0, stream>>>(n1b, WtQKV, bcat, nullptr, qkv,
                                                 M, 3072, 1024, 1024, 1024);

    // 3. sparse strided attention (MFMA) -> bf16 [B,S,D]
    attn3<<<dim3(32, 32), 256, 0, stream>>>(qkv, qkv + SZ, qkv + 2 * SZ, mask, obb);

    // 4. Wo split-K=2 partials, then fused merge(+x+bo) + LN2
    gemm_bt<3><<<dim3(32, 8, 2), 256, 0, stream>>>(obb, WtO, nullptr, nullptr, PpartO,
                                                   M, 1024, 512, 1024, 1024);
    merge_ln<<<M, 256, 0, stream>>>(PpartO, x, bo, g2, bl2, x1, n2b);

    // 6. ff1 = GELU(n2 @ W1 + bf1) -> bf16
    gemm_bt<2><<<dim3(32, 32), 256, 0, stream>>>(n2b, Wt1, bf1, nullptr, ff1b,
                                                 M, 4096, 1024, 1024, 1024);

    // 7. FFN2 split-K=4: partials -> merge (out = x1 + ff1 @ W2 + bf2)
    gemm_bt<3><<<dim3(32, 8, 4), 256, 0, stream>>>(ff1b, Wt2, nullptr, nullptr, Ppart,
                                                   M, 1024, 1024, 4096, 4096);
    ffn2_merge<<<(int)(SZ / 1024), 256, 0, stream>>>(Ppart, x1, bf2, (float*)d_out);
}

// Round 6
// 380.707 us; speedup vs baseline: 7.0393x; 1.0630x over previous
//
#include <hip/hip_runtime.h>
#include <math.h>

typedef unsigned int u32;
typedef unsigned short u16;

#define B_  2
#define S_  2048
#define D_  1024
#define H_  16
#define DK_ 64
#define FF_ 4096
#define NEG_ -1000000000.0f

typedef __attribute__((ext_vector_type(8))) short short8;
typedef __attribute__((ext_vector_type(4))) float floatx4;
typedef __attribute__((ext_vector_type(4))) unsigned short ushort4_t;

__device__ inline u16 f2b(float f) {
    union { float f; u32 u; } v; v.f = f;
    u32 r = (v.u + 0x7fffu + ((v.u >> 16) & 1u)) >> 16;
    return (u16)r;
}
__device__ inline float b2f(u16 b) {
    union { u32 u; float f; } v; v.u = ((u32)b) << 16;
    return v.f;
}

__device__ inline void gl_lds16(const u16* g, u16* l) {
    __builtin_amdgcn_global_load_lds((const __attribute__((address_space(1))) u32*)g,
                                     (__attribute__((address_space(3))) u32*)l, 16, 0, 0);
}

// ------- 4x square (1024x1024) weight transpose+convert in one launch -------
__global__ void tconv4(const float* __restrict__ W0, const float* __restrict__ W1_,
                       const float* __restrict__ W2_, const float* __restrict__ W3,
                       u16* __restrict__ dstBase) {
    __shared__ float tile[32][33];
    int z = blockIdx.z;
    const float* Wm = (z == 0) ? W0 : (z == 1) ? W1_ : (z == 2) ? W2_ : W3;
    u16* Wt = dstBase + (size_t)z * 1024 * 1024;
    const int K = 1024, N = 1024;
    int n0 = blockIdx.x * 32, k0 = blockIdx.y * 32;
    int tx = threadIdx.x & 31, ty = threadIdx.x >> 5;
#pragma unroll
    for (int r = 0; r < 32; r += 8)
        tile[ty + r][tx] = Wm[(size_t)(k0 + ty + r) * N + n0 + tx];
    __syncthreads();
#pragma unroll
    for (int r = 0; r < 32; r += 8)
        Wt[(size_t)(n0 + ty + r) * K + k0 + tx] = f2b(tile[tx][ty + r]);
}

__global__ void tconv(const float* __restrict__ Wm, u16* __restrict__ Wt, int K, int N) {
    __shared__ float tile[32][33];
    int n0 = blockIdx.x * 32, k0 = blockIdx.y * 32;
    int tx = threadIdx.x & 31, ty = threadIdx.x >> 5;
#pragma unroll
    for (int r = 0; r < 32; r += 8)
        tile[ty + r][tx] = Wm[(size_t)(k0 + ty + r) * N + n0 + tx];
    __syncthreads();
#pragma unroll
    for (int r = 0; r < 32; r += 8)
        Wt[(size_t)(n0 + ty + r) * K + k0 + tx] = f2b(tile[tx][ty + r]);
}

__global__ void catbias(const float* __restrict__ bq, const float* __restrict__ bk,
                        const float* __restrict__ bv, float* __restrict__ out) {
    int i = blockIdx.x * 256 + threadIdx.x;
    float v = (i < 1024) ? bq[i] : (i < 2048) ? bk[i - 1024] : bv[i - 2048];
    out[i] = v;
}

// ---- mask tile reduction: tflag[it][jt] = all(mask[128it..][128jt..] != 0) ----
__global__ __launch_bounds__(256)
void mask_tiles(const int* __restrict__ mask, int* __restrict__ tflag) {
    int jt = blockIdx.x, it = blockIdx.y;
    const int* base = mask + (size_t)it * 128 * S_ + jt * 128;
    int t = threadIdx.x;
    int ok = 1;
    for (int e = t; e < 128 * 32; e += 256) {
        int r = e >> 5, c4 = e & 31;
        int4 vv = *(const int4*)&base[(size_t)r * S_ + c4 * 4];
        ok &= (vv.x != 0) & (vv.y != 0) & (vv.z != 0) & (vv.w != 0);
    }
    ok = (int)__all(ok);
    __shared__ int red[4];
    if ((t & 63) == 0) red[t >> 6] = ok;
    __syncthreads();
    if (t == 0) tflag[it * 16 + jt] = red[0] & red[1] & red[2] & red[3];
}

// ---------------- LayerNorm -> bf16 out ----------------
__global__ void ln_bf16(const float* __restrict__ x, const float* __restrict__ g,
                        const float* __restrict__ b, u16* __restrict__ out) {
    int row = blockIdx.x;
    int t = threadIdx.x;
    const float* xr = x + (size_t)row * D_;
    __shared__ float red[256];

    float v[4];
    float s = 0.f;
#pragma unroll
    for (int i = 0; i < 4; i++) { v[i] = xr[i * 256 + t]; s += v[i]; }
    red[t] = s; __syncthreads();
    for (int off = 128; off > 0; off >>= 1) {
        if (t < off) red[t] += red[t + off];
        __syncthreads();
    }
    float mu = red[0] * (1.0f / D_);
    __syncthreads();

    float vs = 0.f;
#pragma unroll
    for (int i = 0; i < 4; i++) { float d = v[i] - mu; vs += d * d; }
    red[t] = vs; __syncthreads();
    for (int off = 128; off > 0; off >>= 1) {
        if (t < off) red[t] += red[t + off];
        __syncthreads();
    }
    float rstd = rsqrtf(red[0] * (1.0f / D_) + 1e-5f);

    u16* outr = out + (size_t)row * D_;
#pragma unroll
    for (int i = 0; i < 4; i++) {
        int col = i * 256 + t;
        outr[col] = f2b((v[i] - mu) * rstd * g[col] + b[col]);
    }
}

// ---- fused split-K merge + residual + bias + LayerNorm (for Wo path) ----
__global__ __launch_bounds__(256)
void merge_ln(const u16* __restrict__ P, const float* __restrict__ x,
              const float* __restrict__ bo, const float* __restrict__ g,
              const float* __restrict__ bl, float* __restrict__ x1,
              u16* __restrict__ n2) {
    const size_t MN = (size_t)B_ * S_ * D_;
    int row = blockIdx.x, t = threadIdx.x;
    size_t base = (size_t)row * D_;
    __shared__ float red[256];

    float v[4];
    float s = 0.f;
#pragma unroll
    for (int i = 0; i < 4; i++) {
        int col = i * 256 + t;
        float val = x[base + col] + bo[col] + b2f(P[base + col]) + b2f(P[MN + base + col]);
        v[i] = val; s += val;
    }
    red[t] = s; __syncthreads();
    for (int off = 128; off > 0; off >>= 1) {
        if (t < off) red[t] += red[t + off];
        __syncthreads();
    }
    float mu = red[0] * (1.0f / D_);
    __syncthreads();

    float vs = 0.f;
#pragma unroll
    for (int i = 0; i < 4; i++) { float d = v[i] - mu; vs += d * d; }
    red[t] = vs; __syncthreads();
    for (int off = 128; off > 0; off >>= 1) {
        if (t < off) red[t] += red[t + off];
        __syncthreads();
    }
    float rstd = rsqrtf(red[0] * (1.0f / D_) + 1e-5f);

#pragma unroll
    for (int i = 0; i < 4; i++) {
        int col = i * 256 + t;
        x1[base + col] = v[i];
        n2[base + col] = f2b((v[i] - mu) * rstd * g[col] + bl[col]);
    }
}

// ---------------- bf16 MFMA GEMM, cross-iteration prefetch double-buffer ---------
// EPI 0: bf16 QKV scatter (Q pre-scaled by 1/8); 1: fp32+residual; 2: bf16 GELU; 3: bf16 partial
template <int EPI>
__global__ __launch_bounds__(256, 4)
void gemm_bt(const u16* __restrict__ A, const u16* __restrict__ Bt,
             const float* __restrict__ bias, const float* __restrict__ R,
             void* __restrict__ Cv, int M, int N, int K, int ldA, int ldB) {
    __shared__ u16 As[2][128 * 32];
    __shared__ u16 Bs[2][128 * 32];
    int tid = threadIdx.x;
    int lane = tid & 63, w = tid >> 6;
    int wm = w >> 1, wn = w & 1;
    int m0 = blockIdx.x * 128, n0 = blockIdx.y * 128;
    size_t koff = (size_t)blockIdx.z * K;

    floatx4 acc[4][4];
#pragma unroll
    for (int a = 0; a < 4; a++)
#pragma unroll
        for (int b2 = 0; b2 < 4; b2++) acc[a][b2] = (floatx4){0.f, 0.f, 0.f, 0.f};

    int r4 = lane >> 2;
    int qg = ((lane & 3) ^ ((lane >> 3) & 3)) * 8;
    const u16* Ag0 = A + (size_t)(m0 + w * 16 + r4) * ldA + koff + qg;
    const u16* Bg0 = Bt + (size_t)(n0 + w * 16 + r4) * ldB + koff + qg;
    const int ldsOff = (w * 16) * 32;

    int c = lane & 15, g = lane >> 4;
    int sw = (g ^ ((c >> 1) & 3)) * 8;

    const int nIter = K >> 5;

    gl_lds16(Ag0, &As[0][ldsOff]);
    gl_lds16(Ag0 + (size_t)64 * ldA, &As[0][ldsOff + 64 * 32]);
    gl_lds16(Bg0, &Bs[0][ldsOff]);
    gl_lds16(Bg0 + (size_t)64 * ldB, &Bs[0][ldsOff + 64 * 32]);

    for (int it = 0; it < nIter; it++) {
        __syncthreads();
        int cur = it & 1, nxt = cur ^ 1;
        if (it + 1 < nIter) {
            int kk = (it + 1) << 5;
            gl_lds16(Ag0 + kk, &As[nxt][ldsOff]);
            gl_lds16(Ag0 + kk + (size_t)64 * ldA, &As[nxt][ldsOff + 64 * 32]);
            gl_lds16(Bg0 + kk, &Bs[nxt][ldsOff]);
            gl_lds16(Bg0 + kk + (size_t)64 * ldB, &Bs[nxt][ldsOff + 64 * 32]);
        }
        short8 fa[4], fb[4];
#pragma unroll
        for (int a = 0; a < 4; a++)
            fa[a] = *(const short8*)&As[cur][(wm * 64 + a * 16 + c) * 32 + sw];
#pragma unroll
        for (int b2 = 0; b2 < 4; b2++)
            fb[b2] = *(const short8*)&Bs[cur][(wn * 64 + b2 * 16 + c) * 32 + sw];
#pragma unroll
        for (int a = 0; a < 4; a++)
#pragma unroll
            for (int b2 = 0; b2 < 4; b2++)
                acc[a][b2] = __builtin_amdgcn_mfma_f32_16x16x32_bf16(fa[a], fb[b2], acc[a][b2], 0, 0, 0);
    }

    int mb = m0 + wm * 64, nb = n0 + wn * 64;
#pragma unroll
    for (int a = 0; a < 4; a++) {
#pragma unroll
        for (int b2 = 0; b2 < 4; b2++) {
            int mrow = mb + a * 16 + g * 4;
            int ncol = nb + b2 * 16 + c;
            float bv = (EPI == 3) ? 0.f : bias[ncol];
#pragma unroll
            for (int r = 0; r < 4; r++) {
                int m = mrow + r;
                float vvv = acc[a][b2][r] + bv;
                if (EPI == 0) {
                    int which = ncol >> 10, col = ncol & 1023;
                    if (which == 0) vvv *= 0.125f;  // fold 1/sqrt(DK) into Q
                    int bb = m >> 11, ss = m & 2047, hh = col >> 6, dk = col & 63;
                    ((u16*)Cv)[(size_t)which * ((size_t)B_ * S_ * D_) +
                               ((((size_t)bb * H_ + hh) * S_) + ss) * DK_ + dk] = f2b(vvv);
                } else if (EPI == 1) {
                    ((float*)Cv)[(size_t)m * N + ncol] = vvv + R[(size_t)m * N + ncol];
                } else if (EPI == 2) {
                    float u = 0.79788456080286536f * fmaf(0.044715f * vvv, vvv * vvv, vvv);
                    float th = 1.f - 2.f / (1.f + __expf(2.f * u));
                    ((u16*)Cv)[(size_t)m * N + ncol] = f2b(0.5f * vvv * (1.f + th));
                } else {
                    ((u16*)Cv)[(size_t)blockIdx.z * M * N + (size_t)m * N + ncol] = f2b(vvv);
                }
            }
        }
    }
}

// ---------------- FFN2 split-K merge: out = x1 + bf2 + sum_z P[z] ----------------
__global__ __launch_bounds__(256)
void ffn2_merge(const u16* __restrict__ P, const float* __restrict__ x1,
                const float* __restrict__ bf2, float* __restrict__ out) {
    const size_t MN = (size_t)B_ * S_ * D_;
    int e = (blockIdx.x * 256 + threadIdx.x) * 4;
    float4 xv = *(const float4*)&x1[e];
    float4 bv = *(const float4*)&bf2[e & 1023];
    float o0 = xv.x + bv.x, o1 = xv.y + bv.y, o2 = xv.z + bv.z, o3 = xv.w + bv.w;
#pragma unroll
    for (int z = 0; z < 4; z++) {
        ushort4_t pv = *(const ushort4_t*)&P[z * MN + e];
        o0 += b2f(pv[0]); o1 += b2f(pv[1]); o2 += b2f(pv[2]); o3 += b2f(pv[3]);
    }
    *(float4*)&out[e] = (float4){o0, o1, o2, o3};
}

// ---------------- MFMA sparse strided attention, 52 KB LDS union -----------------
// block = (b,h, 64 queries). Q pre-scaled by 1/8. tileOK = per-128x128 mask flags.
#define MAXB_ 14
__global__ __launch_bounds__(256)
void attn4(const u16* __restrict__ q, const u16* __restrict__ k,
           const u16* __restrict__ v, const int* __restrict__ mask,
           const int* __restrict__ tileOK, u16* __restrict__ ob) {
    __shared__ u16 sh[26624];            // 53,248 B
    u16* Kw = sh;                        // [192*72] K window; P[64*200] overlays later
    u16* Vt = sh + 13824;                // [64*200] V^T window (built after scores)
    u16* Qs = Vt;                        // [64*72] overlay; dead before Vt is built

    const int i0 = blockIdx.x * 64;
    const int bh = blockIdx.y;
    const int b  = bh >> 4, h = bh & 15;
    const int t  = threadIdx.x;
    const int lane = t & 63, w = t >> 6;
    const int c = lane & 15, g = lane >> 4;
    const int g4 = g * 4;
    const int qloc16 = w * 16;

    const u16* qg = q + ((size_t)bh * S_ + i0) * DK_;
    const u16* kg = k + (size_t)bh * S_ * DK_;
    const u16* vg = v + (size_t)bh * S_ * DK_;

    const int wlo = (i0 >= 128) ? i0 - 128 : 0;
    const int wn  = i0 + 64 - wlo;             // 64 / 128 / 192
    const int nb  = (i0 >= 256) ? (i0 >> 7) - 1 : 0;
    const int jb0 = i0 & 127;
    const int dd0 = i0 - wlo;

    // uniform mask fast-path check (<= 16 scalar flag loads)
    bool allOK = true;
    {
        const int* rowf = tileOK + (i0 >> 7) * 16;
        int jt0 = wlo >> 7, jt1 = (i0 + 63) >> 7;
        for (int jt = jt0; jt <= jt1; jt++) allOK &= (rowf[jt] != 0);
        for (int m = 0; m < nb; m++) allOK &= (rowf[m] != 0);
    }

    // ---- P0: stage Qs + Kw
    for (int e = t; e < 64 * 8; e += 256) {
        int row = e >> 3, dc = e & 7;
        *(short8*)&Qs[row * 72 + dc * 8] = *(const short8*)(qg + row * 64 + dc * 8);
    }
    for (int e = t; e < wn * 8; e += 256) {
        int row = e >> 3, dc = e & 7;
        *(short8*)&Kw[row * 72 + dc * 8] = *(const short8*)(kg + (size_t)(wlo + row) * 64 + dc * 8);
    }
    __syncthreads();

    // ---- P1: band scores -> sbr[m] (every lane holds score for query qloc16+c)
    float sbr[MAXB_];
    {
        short8 qv0 = *(const short8*)&Qs[(qloc16 + c) * 72 + g * 8];
        short8 qv1 = *(const short8*)&Qs[(qloc16 + c) * 72 + 32 + g * 8];
#pragma unroll
        for (int m = 0; m < MAXB_; m++) {
            sbr[m] = NEG_;
            if (m < nb) {
                int jrow = jb0 + (m << 7) + qloc16 + c;
                short8 kv0 = *(const short8*)(kg + (size_t)jrow * 64 + g * 8);
                short8 kv1 = *(const short8*)(kg + (size_t)jrow * 64 + 32 + g * 8);
                float p = 0.f;
#pragma unroll
                for (int i = 0; i < 8; i++) {
                    p += b2f((u16)qv0[i]) * b2f((u16)kv0[i]);
                    p += b2f((u16)qv1[i]) * b2f((u16)kv1[i]);
                }
                p += __shfl_xor(p, 16);
                p += __shfl_xor(p, 32);
                if (!allOK && mask[(size_t)(i0 + qloc16 + c) * S_ + jrow] == 0) p = NEG_;
                sbr[m] = p;
            }
        }
    }

    // ---- P2: window scores via MFMA
    floatx4 sc[12];
#pragma unroll
    for (int ct = 0; ct < 12; ct++) sc[ct] = (floatx4){0.f, 0.f, 0.f, 0.f};
    {
        short8 fa0 = *(const short8*)&Qs[(qloc16 + c) * 72 + g * 8];
        short8 fa1 = *(const short8*)&Qs[(qloc16 + c) * 72 + 32 + g * 8];
#pragma unroll
        for (int ct = 0; ct < 12; ct++) {
            short8 fb0 = *(const short8*)&Kw[(ct * 16 + c) * 72 + g * 8];
            short8 fb1 = *(const short8*)&Kw[(ct * 16 + c) * 72 + 32 + g * 8];
            sc[ct] = __builtin_amdgcn_mfma_f32_16x16x32_bf16(fa0, fb0, sc[ct], 0, 0, 0);
            sc[ct] = __builtin_amdgcn_mfma_f32_16x16x32_bf16(fa1, fb1, sc[ct], 0, 0, 0);
        }
    }

    // ---- P3: causal/range mask (+fallback user mask) + softmax stats
#pragma unroll
    for (int ct = 0; ct < 12; ct++) {
        int cidx = ct * 16 + c;
        int j = wlo + cidx;
#pragma unroll
        for (int r = 0; r < 4; r++) {
            int qloc = qloc16 + g4 + r;
            int d = dd0 + qloc - cidx;
            bool ok = (d >= 0) && (d <= 128);
            if (ok && !allOK) ok = (mask[(size_t)(i0 + qloc) * S_ + j] != 0);
            sc[ct][r] = ok ? sc[ct][r] : NEG_;
        }
    }

    float mv[4], inv[4];
#pragma unroll
    for (int r = 0; r < 4; r++) {
        float bs[MAXB_];
#pragma unroll
        for (int m = 0; m < MAXB_; m++)
            bs[m] = (m < nb) ? __shfl(sbr[m], g4 + r, 64) : NEG_;
        float mm = -1e30f;
#pragma unroll
        for (int ct = 0; ct < 12; ct++) mm = fmaxf(mm, sc[ct][r]);
        mm = fmaxf(mm, __shfl_xor(mm, 1));
        mm = fmaxf(mm, __shfl_xor(mm, 2));
        mm = fmaxf(mm, __shfl_xor(mm, 4));
        mm = fmaxf(mm, __shfl_xor(mm, 8));
#pragma unroll
        for (int m = 0; m < MAXB_; m++)
            if (m < nb) mm = fmaxf(mm, bs[m]);
        float sum = 0.f;
#pragma unroll
        for (int ct = 0; ct < 12; ct++) {
            float e = __expf(sc[ct][r] - mm);
            sc[ct][r] = e;
            sum += e;
        }
        sum += __shfl_xor(sum, 1);
        sum += __shfl_xor(sum, 2);
        sum += __shfl_xor(sum, 4);
        sum += __shfl_xor(sum, 8);
#pragma unroll
        for (int m = 0; m < MAXB_; m++)
            if (m < nb) sum += __expf(bs[m] - mm);
        mv[r] = mm;
        inv[r] = 1.f / sum;
    }

    // ---- P4: write P over Kw; build Vt over Qs (both dead now)
    __syncthreads();
    u16* P = Kw;
#pragma unroll
    for (int ct = 0; ct < 12; ct++)
#pragma unroll
        for (int r = 0; r < 4; r++)
            P[(qloc16 + g4 + r) * 200 + ct * 16 + c] = f2b(sc[ct][r]);
#pragma unroll
    for (int dc = 0; dc < 8; dc++) {
        for (int jl = t; jl < 192; jl += 256) {
            short8 val = {0, 0, 0, 0, 0, 0, 0, 0};
            if (jl < wn) val = *(const short8*)(vg + (size_t)(wlo + jl) * 64 + dc * 8);
#pragma unroll
            for (int i = 0; i < 8; i++) Vt[(dc * 8 + i) * 200 + jl] = (u16)val[i];
        }
    }
    __syncthreads();

    // ---- P5: window PV via MFMA
    floatx4 o[4];
#pragma unroll
    for (int nt = 0; nt < 4; nt++) o[nt] = (floatx4){0.f, 0.f, 0.f, 0.f};
#pragma unroll
    for (int ks = 0; ks < 6; ks++) {
        short8 pa = *(const short8*)&P[(qloc16 + c) * 200 + ks * 32 + g * 8];
#pragma unroll
        for (int nt = 0; nt < 4; nt++) {
            short8 vb = *(const short8*)&Vt[(nt * 16 + c) * 200 + ks * 32 + g * 8];
            o[nt] = __builtin_amdgcn_mfma_f32_16x16x32_bf16(pa, vb, o[nt], 0, 0, 0);
        }
    }

    // ---- P6: band PV via per-lane register loads (no LDS, no vmcnt(0) serialization)
#pragma unroll
    for (int m = 0; m < MAXB_; m++) {
        if (m < nb) {
            int vbase = jb0 + (m << 7) + qloc16 + g4;
            u16 vv[4][4];
#pragma unroll
            for (int r = 0; r < 4; r++)
#pragma unroll
                for (int nt = 0; nt < 4; nt++)
                    vv[r][nt] = vg[(size_t)(vbase + r) * 64 + nt * 16 + c];
#pragma unroll
            for (int r = 0; r < 4; r++) {
                float bs = __shfl(sbr[m], g4 + r, 64);
                float pb = __expf(bs - mv[r]);
#pragma unroll
                for (int nt = 0; nt < 4; nt++)
                    o[nt][r] += pb * b2f(vv[r][nt]);
            }
        }
    }

    // ---- P7: normalize + write [B,S,D] bf16
#pragma unroll
    for (int nt = 0; nt < 4; nt++) {
#pragma unroll
        for (int r = 0; r < 4; r++) {
            int qi = i0 + qloc16 + g4 + r;
            ob[((size_t)b * S_ + qi) * D_ + h * 64 + nt * 16 + c] = f2b(o[nt][r] * inv[r]);
        }
    }
}

extern "C" void kernel_launch(void* const* d_in, const int* in_sizes, int n_in,
                              void* d_out, int out_size, void* d_ws, size_t ws_size,
                              hipStream_t stream) {
    const float* x    = (const float*)d_in[0];
    const int*   mask = (const int*)  d_in[1];
    const float* Wq   = (const float*)d_in[2];
    const float* bq   = (const float*)d_in[3];
    const float* Wk   = (const float*)d_in[4];
    const float* bk   = (const float*)d_in[5];
    const float* Wv   = (const float*)d_in[6];
    const float* bv   = (const float*)d_in[7];
    const float* Wo   = (const float*)d_in[8];
    const float* bo   = (const float*)d_in[9];
    const float* W1   = (const float*)d_in[10];
    const float* bf1  = (const float*)d_in[11];
    const float* W2   = (const float*)d_in[12];
    const float* bf2  = (const float*)d_in[13];
    const float* g1   = (const float*)d_in[14];
    const float* bl1  = (const float*)d_in[15];
    const float* g2   = (const float*)d_in[16];
    const float* bl2  = (const float*)d_in[17];

    char* wsb = (char*)d_ws;
    const size_t MB = 1024 * 1024;
    u16*   WtQKV  = (u16*)(wsb + 0);          // 6 MB; WtO contiguous after
    u16*   WtO    = (u16*)(wsb + 6 * MB);     // 2 MB
    u16*   Wt1    = (u16*)(wsb + 8 * MB);     // 8 MB
    u16*   Wt2    = (u16*)(wsb + 16 * MB);    // 8 MB
    u16*   n1b    = (u16*)(wsb + 24 * MB);    // 8 MB (reused as n2b)
    u16*   qkv    = (u16*)(wsb + 32 * MB);    // 24 MB (dead after attn)
    u16*   obb    = (u16*)(wsb + 56 * MB);    // 8 MB (dead after Wo gemm)
    float* x1     = (float*)(wsb + 32 * MB);  // 16 MB over dead q|k (live thru merge)
    u16*   ff1b   = (u16*)(wsb + 48 * MB);    // 33.5 MB over dead v|obb
    u16*   Ppart  = (u16*)(wsb + 82 * MB);    // 32 MB: FFN2 4x bf16 partials
    u16*   PpartO = (u16*)(wsb + 82 * MB);    // 16 MB: Wo 2x partials (dead before FFN2)
    float* bcat   = (float*)(wsb + 114 * MB); // 12 KB
    int*   tflag  = (int*)(wsb + 115 * MB);   // 1 KB
    u16*   n2b    = n1b;

    const int M = B_ * S_;  // 4096
    const size_t SZ = (size_t)B_ * S_ * D_;

    // 0. mask tile flags, weight transpose + convert, bias concat
    mask_tiles<<<dim3(16, 16), 256, 0, stream>>>(mask, tflag);
    tconv4<<<dim3(32, 32, 4), 256, 0, stream>>>(Wq, Wk, Wv, Wo, WtQKV);
    tconv<<<dim3(128, 32), 256, 0, stream>>>(W1, Wt1, 1024, 4096);
    tconv<<<dim3(32, 128), 256, 0, stream>>>(W2, Wt2, 4096, 1024);
    catbias<<<12, 256, 0, stream>>>(bq, bk, bv, bcat);

    // 1. LN1 -> bf16
    ln_bf16<<<M, 256, 0, stream>>>(x, g1, bl1, n1b);

    // 2. fused QKV projection (N=3072) -> bf16 [B,H,S,DK] x3 (Q pre-scaled 1/8)
    gemm_bt<0><<<dim3(32, 24), 256, 0, stream>>>(n1b, WtQKV, bcat, nullptr, qkv,
                                                 M, 3072, 1024, 1024, 1024);

    // 3. sparse strided attention (MFMA) -> bf16 [B,S,D]
    attn4<<<dim3(32, 32), 256, 0, stream>>>(qkv, qkv + SZ, qkv + 2 * SZ, mask, tflag, obb);

    // 4. Wo split-K=2 partials, then fused merge(+x+bo) + LN2
    gemm_bt<3><<<dim3(32, 8, 2), 256, 0, stream>>>(obb, WtO, nullptr, nullptr, PpartO,
                                                   M, 1024, 512, 1024, 1024);
    merge_ln<<<M, 256, 0, stream>>>(PpartO, x, bo, g2, bl2, x1, n2b);

    // 6. ff1 = GELU(n2 @ W1 + bf1) -> bf16
    gemm_bt<2><<<dim3(32, 32), 256, 0, stream>>>(n2b, Wt1, bf1, nullptr, ff1b,
                                                 M, 4096, 1024, 1024, 1024);

    // 7. FFN2 split-K=4: partials -> merge (out = x1 + ff1 @ W2 + bf2)
    gemm_bt<3><<<dim3(32, 8, 4), 256, 0, stream>>>(ff1b, Wt2, nullptr, nullptr, Ppart,
                                                   M, 1024, 1024, 4096, 4096);
    ffn2_merge<<<(int)(SZ / 1024), 256, 0, stream>>>(Ppart, x1, bf2, (float*)d_out);
}